// Round 13
// baseline (577.349 us; speedup 1.0000x reference)
//
#include <hip/hip_runtime.h>
#include <hip/hip_bf16.h>
#include <math.h>

#define NNODES  50000
#define NEDGES  200000
#define NTOT    250000      // E + N self loops
#define EMB     300
#define LDK     320         // padded K stride (bf16 h / mh / weights)
#define MPAD    50048       // 391 * 128 (GEMM M padding)
#define NLAYERS 5
#define NSCAN   49          // ceil(NNODES / 1024)
#define NPW     8           // nodes per wave in k_aggr (amortize prm prologue)

struct EdgeRec { int r; float c0, c1; };

typedef __attribute__((ext_vector_type(8))) short short8;
typedef __attribute__((ext_vector_type(4))) float floatx4;

__device__ inline void gll16(const void* g, void* s) {
    __builtin_amdgcn_global_load_lds((const __attribute__((address_space(1))) unsigned*)g,
                                     (__attribute__((address_space(3))) unsigned*)s, 16, 0, 0);
}

// ---------------- weight convert: wb[l][320][320] = bf16(mlp_w[l][300][300]) zero-padded ----------------
__global__ void k_cvt(const float* __restrict__ w, __hip_bfloat16* __restrict__ wb) {
    int idx = blockIdx.x * 256 + threadIdx.x;
    if (idx >= 5 * 320 * 320) return;
    int l = idx / 102400, r = idx % 102400, n = r / 320, k = r % 320;
    float v = (n < 300 && k < 300) ? w[l * 90000 + n * 300 + k] : 0.f;
    wb[idx] = __float2bfloat16(v);
}

// ---------------- metal-path weight packs: wcat[512][320] = [wq; ml_w], wkTb[320][256] = wk^T ----------------
__global__ void k_cvt2(const float* __restrict__ wq, const float* __restrict__ ml_w,
                       const float* __restrict__ wk,
                       __hip_bfloat16* __restrict__ wcat, __hip_bfloat16* __restrict__ wkTb) {
    int idx = blockIdx.x * 256 + threadIdx.x;
    if (idx < 512 * 320) {
        int r = idx / 320, k = idx % 320;
        float v = 0.f;
        if (k < 300) v = (r < 256) ? wq[r * 300 + k] : ml_w[(r - 256) * 300 + k];
        wcat[idx] = __float2bfloat16(v);
        return;
    }
    idx -= 512 * 320;
    if (idx < 320 * 256) {
        int c = idx / 256, j = idx % 256;
        float v = (c < 300) ? wk[j * 300 + c] : 0.f;
        wkTb[idx] = __float2bfloat16(v);
    }
}

// ---------------- init/head weight packs ----------------
__global__ void k_cvt3(const float* __restrict__ xf, const float* __restrict__ xw,
                       const float* __restrict__ wv, const float* __restrict__ lg_w,
                       const float* __restrict__ ph1_w, const float* __restrict__ me1_w,
                       __hip_bfloat16* __restrict__ xfb, __hip_bfloat16* __restrict__ xwTb,
                       __hip_bfloat16* __restrict__ wvB, __hip_bfloat16* __restrict__ lgwB,
                       __hip_bfloat16* __restrict__ ph1wb, float* __restrict__ me1wT) {
    int idx = blockIdx.x * 256 + threadIdx.x;
    if (idx < 1601536) {
        int n = idx >> 5, k = idx & 31;
        xfb[idx] = __float2bfloat16((n < 50000 && k < 16) ? xf[n * 16 + k] : 0.f);
        return;
    }
    idx -= 1601536;
    if (idx < 10240) {
        int n = idx >> 5, k = idx & 31;
        xwTb[idx] = __float2bfloat16((n < 300 && k < 16) ? xw[k * 300 + n] : 0.f);
        return;
    }
    idx -= 10240;
    if (idx < 81920) { int r = idx / 320, k = idx % 320;
        wvB[idx] = __float2bfloat16((k < 300) ? wv[r * 300 + k] : 0.f); return; }
    idx -= 81920;
    if (idx < 81920) { int r = idx / 320, k = idx % 320;
        lgwB[idx] = __float2bfloat16((k < 300) ? lg_w[r * 300 + k] : 0.f); return; }
    idx -= 81920;
    if (idx < 131072) { ph1wb[idx] = __float2bfloat16(ph1_w[idx]); return; }
    idx -= 131072;
    if (idx < 5100) { int r = idx / 17, c = idx % 17; me1wT[c * 300 + r] = me1_w[idx]; }
}

// ---------------- mf = me1b + me2[mt] + mfeat @ me1wT, bf16 [1024,320] (pads pre-zeroed) ----------------
__global__ __launch_bounds__(256) void k_mf(const int* __restrict__ mt, const float* __restrict__ mfeat,
                                            const float* __restrict__ me1wT, const float* __restrict__ me1b,
                                            const float* __restrict__ me2,
                                            __hip_bfloat16* __restrict__ mfb) {
    int idx = blockIdx.x * 256 + threadIdx.x;
    if (idx >= 1000 * 300) return;
    int g = idx / 300, c = idx % 300;
    float v = me1b[c] + me2[(size_t)mt[g] * 300 + c];
    #pragma unroll
    for (int k = 0; k < 17; ++k) v += mfeat[g * 17 + k] * me1wT[k * 300 + c];
    mfb[(size_t)g * 320 + c] = __float2bfloat16(v);
}

// ---------------- generic 128x64 MFMA GEMM for metal path (modes 0/1) ----------------
__global__ __launch_bounds__(256) void k_mm(const __hip_bfloat16* __restrict__ A, int lda,
                                            const __hip_bfloat16* __restrict__ B, int ldb,
                                            int K, int mode,
                                            const float* __restrict__ mlb,
                                            __hip_bfloat16* __restrict__ qb,
                                            float* __restrict__ metal2,
                                            float* __restrict__ qkout) {
    __shared__ __hip_bfloat16 As[128 * 32];
    __shared__ __hip_bfloat16 Bs[64 * 32];
    int tid = threadIdx.x, lane = tid & 63, w = tid >> 6;
    int row0 = blockIdx.x * 128, col0 = blockIdx.y * 64;

    floatx4 acc[2][4];
    #pragma unroll
    for (int i = 0; i < 2; ++i)
        #pragma unroll
        for (int j = 0; j < 4; ++j) acc[i][j] = (floatx4){0.f, 0.f, 0.f, 0.f};

    const __hip_bfloat16* ga0 = A + (size_t)(row0 + w * 32 + (lane >> 2)) * lda + (lane & 3) * 8;
    const __hip_bfloat16* ga1 = ga0 + (size_t)16 * lda;
    const __hip_bfloat16* gb  = B + (size_t)(col0 + w * 16 + (lane >> 2)) * ldb + (lane & 3) * 8;
    __hip_bfloat16* sa0 = &As[(w * 32) * 32];
    __hip_bfloat16* sa1 = &As[(w * 32 + 16) * 32];
    __hip_bfloat16* sb  = &Bs[(w * 16) * 32];

    int m15 = lane & 15, kof = (lane >> 4) * 8;

    for (int k0 = 0; k0 < K; k0 += 32) {
        __syncthreads();
        gll16(ga0 + k0, sa0);
        gll16(ga1 + k0, sa1);
        gll16(gb  + k0, sb);
        __syncthreads();

        short8 a[2], b[4];
        a[0] = *(const short8*)&As[(w * 32 +      m15) * 32 + kof];
        a[1] = *(const short8*)&As[(w * 32 + 16 + m15) * 32 + kof];
        #pragma unroll
        for (int nt = 0; nt < 4; ++nt)
            b[nt] = *(const short8*)&Bs[(nt * 16 + m15) * 32 + kof];

        #pragma unroll
        for (int mt = 0; mt < 2; ++mt)
            #pragma unroll
            for (int nt = 0; nt < 4; ++nt)
                acc[mt][nt] = __builtin_amdgcn_mfma_f32_16x16x32_bf16(a[mt], b[nt], acc[mt][nt], 0, 0, 0);
    }

    int rbase = row0 + w * 32 + (lane >> 4) * 4;
    #pragma unroll
    for (int mt = 0; mt < 2; ++mt)
        #pragma unroll
        for (int i = 0; i < 4; ++i) {
            int gr = rbase + mt * 16 + i;
            #pragma unroll
            for (int nt = 0; nt < 4; ++nt) {
                int gc = col0 + nt * 16 + m15;
                float v = acc[mt][nt][i];
                if (mode == 0) {
                    if (gc < 256) qb[(size_t)gr * 256 + gc] = __float2bfloat16(v);
                    else if (gr < 1000) metal2[(size_t)gr * 256 + (gc - 256)] = fmaxf(v + mlb[gc - 256], 0.f);
                } else {
                    if (gc < 300 && gr < 1000) qkout[(size_t)gr * 320 + gc] = v;
                }
            }
        }
}

// ---------------- generic 128x64 MFMA GEMM, raw fp32 store (head path) ----------------
__global__ __launch_bounds__(256) void k_mm2(const __hip_bfloat16* __restrict__ A, int lda,
                                             const __hip_bfloat16* __restrict__ B, int ldb,
                                             int K, float* __restrict__ C, int ldc) {
    __shared__ __hip_bfloat16 As[128 * 32];
    __shared__ __hip_bfloat16 Bs[64 * 32];
    int tid = threadIdx.x, lane = tid & 63, w = tid >> 6;
    int row0 = blockIdx.x * 128, col0 = blockIdx.y * 64;

    floatx4 acc[2][4];
    #pragma unroll
    for (int i = 0; i < 2; ++i)
        #pragma unroll
        for (int j = 0; j < 4; ++j) acc[i][j] = (floatx4){0.f, 0.f, 0.f, 0.f};

    const __hip_bfloat16* ga0 = A + (size_t)(row0 + w * 32 + (lane >> 2)) * lda + (lane & 3) * 8;
    const __hip_bfloat16* ga1 = ga0 + (size_t)16 * lda;
    const __hip_bfloat16* gb  = B + (size_t)(col0 + w * 16 + (lane >> 2)) * ldb + (lane & 3) * 8;
    __hip_bfloat16* sa0 = &As[(w * 32) * 32];
    __hip_bfloat16* sa1 = &As[(w * 32 + 16) * 32];
    __hip_bfloat16* sb  = &Bs[(w * 16) * 32];

    int m15 = lane & 15, kof = (lane >> 4) * 8;

    for (int k0 = 0; k0 < K; k0 += 32) {
        __syncthreads();
        gll16(ga0 + k0, sa0);
        gll16(ga1 + k0, sa1);
        gll16(gb  + k0, sb);
        __syncthreads();

        short8 a[2], b[4];
        a[0] = *(const short8*)&As[(w * 32 +      m15) * 32 + kof];
        a[1] = *(const short8*)&As[(w * 32 + 16 + m15) * 32 + kof];
        #pragma unroll
        for (int nt = 0; nt < 4; ++nt)
            b[nt] = *(const short8*)&Bs[(nt * 16 + m15) * 32 + kof];

        #pragma unroll
        for (int mt = 0; mt < 2; ++mt)
            #pragma unroll
            for (int nt = 0; nt < 4; ++nt)
                acc[mt][nt] = __builtin_amdgcn_mfma_f32_16x16x32_bf16(a[mt], b[nt], acc[mt][nt], 0, 0, 0);
    }

    int rbase = row0 + w * 32 + (lane >> 4) * 4;
    #pragma unroll
    for (int mt = 0; mt < 2; ++mt)
        #pragma unroll
        for (int i = 0; i < 4; ++i) {
            int gr = rbase + mt * 16 + i;
            #pragma unroll
            for (int nt = 0; nt < 4; ++nt)
                C[(size_t)gr * ldc + col0 + nt * 16 + m15] = acc[mt][nt][i];
        }
}

// ---------------- node init as MFMA GEMM: h = bf16(xemb[xt] + xfb @ xwTb^T), K=32 (one iter) ----------------
__global__ __launch_bounds__(256) void k_initg(const __hip_bfloat16* __restrict__ A,
                                               const __hip_bfloat16* __restrict__ B,
                                               const int* __restrict__ xt,
                                               const float* __restrict__ xemb,
                                               __hip_bfloat16* __restrict__ h) {
    int b = blockIdx.x;
    int rowblk = (b >> 4) * 8 + (b & 7);
    if (rowblk >= 391) return;
    int row0 = rowblk * 128;
    int col0 = ((b >> 3) & 1) * 160;

    __shared__ __hip_bfloat16 As[128 * 32];
    __shared__ __hip_bfloat16 Bs[160 * 32];
    int tid = threadIdx.x;
    int lane = tid & 63, w = tid >> 6;

    floatx4 acc[2][10];
    #pragma unroll
    for (int i = 0; i < 2; ++i)
        #pragma unroll
        for (int j = 0; j < 10; ++j) acc[i][j] = (floatx4){0.f, 0.f, 0.f, 0.f};

    const __hip_bfloat16* ga0 = A + (size_t)(row0 + w * 32 + (lane >> 2)) * 32 + (lane & 3) * 8;
    const __hip_bfloat16* ga1 = ga0 + (size_t)16 * 32;
    __hip_bfloat16* sa0 = &As[(w * 32) * 32];
    __hip_bfloat16* sa1 = &As[(w * 32 + 16) * 32];
    int brow0 = (w < 2) ? w * 48 : 96 + (w - 2) * 32;
    int nb = (w < 2) ? 3 : 2;
    const __hip_bfloat16* gb = B + (size_t)(col0 + brow0 + (lane >> 2)) * 32 + (lane & 3) * 8;
    __hip_bfloat16* sb = &Bs[brow0 * 32];

    int m15 = lane & 15, kof = (lane >> 4) * 8;

    gll16(ga0, sa0);
    gll16(ga1, sa1);
    for (int i = 0; i < nb; ++i)
        gll16(gb + (size_t)i * 16 * 32, sb + i * 16 * 32);
    __syncthreads();

    short8 a[2], bb[10];
    a[0] = *(const short8*)&As[(w * 32 +      m15) * 32 + kof];
    a[1] = *(const short8*)&As[(w * 32 + 16 + m15) * 32 + kof];
    #pragma unroll
    for (int nt = 0; nt < 10; ++nt)
        bb[nt] = *(const short8*)&Bs[(nt * 16 + m15) * 32 + kof];

    #pragma unroll
    for (int mt = 0; mt < 2; ++mt)
        #pragma unroll
        for (int nt = 0; nt < 10; ++nt)
            acc[mt][nt] = __builtin_amdgcn_mfma_f32_16x16x32_bf16(a[mt], bb[nt], acc[mt][nt], 0, 0, 0);

    int rbase = row0 + w * 32 + (lane >> 4) * 4;
    #pragma unroll
    for (int mt = 0; mt < 2; ++mt)
        #pragma unroll
        for (int i = 0; i < 4; ++i) {
            int gr = rbase + mt * 16 + i;
            if (gr < NNODES) {
                const float* er = xemb + (size_t)xt[gr] * 300;
                #pragma unroll
                for (int nt = 0; nt < 10; ++nt) {
                    int gc = col0 + nt * 16 + m15;
                    if (gc < 300)
                        h[(size_t)gr * LDK + gc] = __float2bfloat16(acc[mt][nt][i] + er[gc]);
                }
            }
        }
}

// ---------------- CSR build ----------------
__global__ void k_count(const int* __restrict__ ei, int* __restrict__ cnt) {
    int e = blockIdx.x * blockDim.x + threadIdx.x;
    if (e >= NTOT) return;
    int c = (e < NEDGES) ? ei[NEDGES + e] : (e - NEDGES);
    atomicAdd(&cnt[c], 1);
}

__global__ __launch_bounds__(1024) void k_scan1(const int* __restrict__ cnt, int* __restrict__ off,
                                                int* __restrict__ bsum) {
    int tid = threadIdx.x;
    int gid = blockIdx.x * 1024 + tid;
    int lane = tid & 63, wv = tid >> 6;
    int v = (gid < NNODES) ? cnt[gid] : 0;
    int x = v;
    #pragma unroll
    for (int s = 1; s < 64; s <<= 1) {
        int t = __shfl_up(x, s, 64);
        if (lane >= s) x += t;
    }
    __shared__ int wsum[16];
    if (lane == 63) wsum[wv] = x;
    __syncthreads();
    if (wv == 0) {
        int w = (lane < 16) ? wsum[lane] : 0;
        #pragma unroll
        for (int s = 1; s < 16; s <<= 1) {
            int t = __shfl_up(w, s, 64);
            if (lane >= s) w += t;
        }
        if (lane < 16) wsum[lane] = w;
    }
    __syncthreads();
    int base = (wv > 0) ? wsum[wv - 1] : 0;
    int incl = x + base;
    if (gid < NNODES) off[gid] = incl - v;
    if (tid == 1023) bsum[blockIdx.x] = incl;
}

__global__ __launch_bounds__(64) void k_scan2(int* __restrict__ bsum) {
    int lane = threadIdx.x;
    int v = (lane < NSCAN) ? bsum[lane] : 0;
    int x = v;
    #pragma unroll
    for (int s = 1; s < 64; s <<= 1) {
        int t = __shfl_up(x, s, 64);
        if (lane >= s) x += t;
    }
    if (lane < NSCAN) bsum[lane] = x - v;
}

__global__ __launch_bounds__(1024) void k_scan3(int* __restrict__ off, const int* __restrict__ bsum) {
    int gid = blockIdx.x * 1024 + threadIdx.x;
    if (gid < NNODES) off[gid] += bsum[blockIdx.x];
    if (gid == 0) off[NNODES] = NTOT;
}

__global__ void k_fill(const int* __restrict__ ei, const float* __restrict__ ea,
                       const int* __restrict__ off, int* __restrict__ cur,
                       EdgeRec* __restrict__ pack) {
    int e = blockIdx.x * blockDim.x + threadIdx.x;
    if (e >= NTOT) return;
    int r, c; float c0, c1;
    if (e < NEDGES) { r = ei[e]; c = ei[NEDGES + e]; c0 = ea[2 * e]; c1 = ea[2 * e + 1]; }
    else            { r = c = e - NEDGES; c0 = 0.f; c1 = 4.f; }
    int p = atomicAdd(&cur[c], 1);
    EdgeRec rec; rec.r = r; rec.c0 = c0; rec.c1 = c1;
    pack[off[c] + p] = rec;
}

// ---------------- per-layer precompute, all layers in one launch ----------------
__global__ __launch_bounds__(64) void k_prep(const float* __restrict__ mlp_w, const float* __restrict__ ew1,
                                             const float* __restrict__ mlp_b, const float* __restrict__ bn_g,
                                             const float* __restrict__ bn_b, const float* __restrict__ bn_rm,
                                             const float* __restrict__ bn_rv, float* __restrict__ prm) {
    int j = blockIdx.x, l = blockIdx.y;
    int lane = threadIdx.x;
    const float* W  = mlp_w + (size_t)l * 90000 + (size_t)j * 300;
    const float* ew = ew1 + l * 600;
    float a0 = 0.f, a1 = 0.f;
    #pragma unroll
    for (int i = 0; i < 5; ++i) {
        int k = lane + i * 64;
        if (k < 300) {
            float w = W[k];
            a0 += w * ew[k];
            a1 += w * ew[300 + k];
        }
    }
    #pragma unroll
    for (int s = 32; s > 0; s >>= 1) { a0 += __shfl_xor(a0, s, 64); a1 += __shfl_xor(a1, s, 64); }
    if (lane == 0) {
        float* p = prm + l * 1520;
        p[j] = a0;
        p[304 + j] = a1;
        p[608 + j] = mlp_b[l * 300 + j];
        float sc = bn_g[l * 300 + j] * rsqrtf(bn_rv[l * 300 + j] + 1e-5f);
        p[912 + j] = sc;
        p[1216 + j] = bn_b[l * 300 + j] - bn_rm[l * 300 + j] * sc;
    }
}

// ---------------- MFMA GEMM (layers): BK=64 LDS-staged 128x160 block, XCD-swizzled grid ----------------
// BK=64 halves the per-K-chunk barrier drains (5 instead of 10). LDS 36 KB.
__global__ __launch_bounds__(256) void k_gemm(const __hip_bfloat16* __restrict__ A,
                                              const __hip_bfloat16* __restrict__ B,
                                              __hip_bfloat16* __restrict__ C) {
    int b = blockIdx.x;
    int rowblk = (b >> 4) * 8 + (b & 7);
    if (rowblk >= 391) return;
    int row0 = rowblk * 128;
    int col0 = ((b >> 3) & 1) * 160;

    __shared__ __hip_bfloat16 As[128 * 64];
    __shared__ __hip_bfloat16 Bs[160 * 64];
    int tid = threadIdx.x;
    int lane = tid & 63, w = tid >> 6;

    floatx4 acc[2][10];
    #pragma unroll
    for (int i = 0; i < 2; ++i)
        #pragma unroll
        for (int j = 0; j < 10; ++j) acc[i][j] = (floatx4){0.f, 0.f, 0.f, 0.f};

    // staging: each gll16 covers 8 rows of 128 B (lane>>3 = row, lane&7 = 16B chunk)
    int srow = lane >> 3, schunk = (lane & 7) * 8;
    // A: wave w stages rows w*32 .. w*32+31 (4 gll16 of 8 rows)
    const __hip_bfloat16* gaBase = A + (size_t)(row0 + w * 32 + srow) * LDK + schunk;
    __hip_bfloat16* saBase = &As[(w * 32) * 64];
    // B: waves 0,1 stage 48 rows (6 gll16); waves 2,3 stage 32 rows (4 gll16)
    int brow0 = (w < 2) ? w * 48 : 96 + (w - 2) * 32;
    int nbg = (w < 2) ? 6 : 4;
    const __hip_bfloat16* gbBase = B + (size_t)(col0 + brow0 + srow) * LDK + schunk;
    __hip_bfloat16* sbBase = &Bs[brow0 * 64];

    int m15 = lane & 15, kof = (lane >> 4) * 8;

    for (int k0 = 0; k0 < LDK; k0 += 64) {
        __syncthreads();
        #pragma unroll
        for (int g = 0; g < 4; ++g)
            gll16(gaBase + (size_t)(g * 8) * LDK + k0, saBase + g * 8 * 64);
        for (int g = 0; g < nbg; ++g)
            gll16(gbBase + (size_t)(g * 8) * LDK + k0, sbBase + g * 8 * 64);
        __syncthreads();

        #pragma unroll
        for (int half = 0; half < 2; ++half) {
            int ko = kof + half * 32;
            short8 a[2], bb[10];
            a[0] = *(const short8*)&As[(w * 32 +      m15) * 64 + ko];
            a[1] = *(const short8*)&As[(w * 32 + 16 + m15) * 64 + ko];
            #pragma unroll
            for (int nt = 0; nt < 10; ++nt)
                bb[nt] = *(const short8*)&Bs[(nt * 16 + m15) * 64 + ko];

            #pragma unroll
            for (int mt = 0; mt < 2; ++mt)
                #pragma unroll
                for (int nt = 0; nt < 10; ++nt)
                    acc[mt][nt] = __builtin_amdgcn_mfma_f32_16x16x32_bf16(a[mt], bb[nt], acc[mt][nt], 0, 0, 0);
        }
    }

    int rbase = row0 + w * 32 + (lane >> 4) * 4;
    #pragma unroll
    for (int mt = 0; mt < 2; ++mt)
        #pragma unroll
        for (int i = 0; i < 4; ++i) {
            long gr = rbase + mt * 16 + i;
            #pragma unroll
            for (int nt = 0; nt < 10; ++nt)
                C[gr * LDK + col0 + nt * 16 + m15] = __float2bfloat16(acc[mt][nt][i]);
        }
}

// ---------------- aggregate: wave handles NPW sequential nodes (prm prologue amortized) ----------------
__global__ __launch_bounds__(256) void k_aggr(const __hip_bfloat16* __restrict__ mh,
                                              const EdgeRec* __restrict__ pack,
                                              const int* __restrict__ off, const float* __restrict__ prm,
                                              __hip_bfloat16* __restrict__ h, int do_relu) {
    int wave = threadIdx.x >> 6;
    int lane = threadIdx.x & 63;
    int n0 = (blockIdx.x * 4 + wave) * NPW;
    if (n0 >= NNODES) return;

    float u0[3][2], u1[3][2], bv[3][2], sc[3][2], sh[3][2];
    #pragma unroll
    for (int i = 0; i < 3; ++i) {
        int j = 2 * lane + 128 * i;
        #pragma unroll
        for (int t = 0; t < 2; ++t) {
            bool ok = (j + t) < 300;
            u0[i][t] = ok ? prm[j + t]        : 0.f;
            u1[i][t] = ok ? prm[304 + j + t]  : 0.f;
            bv[i][t] = ok ? prm[608 + j + t]  : 0.f;
            sc[i][t] = ok ? prm[912 + j + t]  : 0.f;
            sh[i][t] = ok ? prm[1216 + j + t] : 0.f;
        }
    }

    int nend = (n0 + NPW < NNODES) ? n0 + NPW : NNODES;
    for (int n = n0; n < nend; ++n) {
        float acc[3][2];
        #pragma unroll
        for (int i = 0; i < 3; ++i) { acc[i][0] = 0.f; acc[i][1] = 0.f; }
        int p0 = off[n], p1 = off[n + 1];
        int p = p0;
        for (; p + 1 < p1; p += 2) {
            EdgeRec e0 = pack[p], e1 = pack[p + 1];
            const __hip_bfloat16* b0 = mh + (size_t)e0.r * LDK;
            const __hip_bfloat16* b1 = mh + (size_t)e1.r * LDK;
            __hip_bfloat162 hv0[3], hv1[3];
            #pragma unroll
            for (int i = 0; i < 3; ++i) {
                int j = 2 * lane + 128 * i;
                if (j < 300) {
                    hv0[i] = *(const __hip_bfloat162*)&b0[j];
                    hv1[i] = *(const __hip_bfloat162*)&b1[j];
                }
            }
            #pragma unroll
            for (int i = 0; i < 3; ++i) {
                int j = 2 * lane + 128 * i;
                if (j < 300) {
                    acc[i][0] += fmaxf(__bfloat162float(hv0[i].x) + e0.c0 * u0[i][0] + e0.c1 * u1[i][0] + bv[i][0], 0.f);
                    acc[i][1] += fmaxf(__bfloat162float(hv0[i].y) + e0.c0 * u0[i][1] + e0.c1 * u1[i][1] + bv[i][1], 0.f);
                    acc[i][0] += fmaxf(__bfloat162float(hv1[i].x) + e1.c0 * u0[i][0] + e1.c1 * u1[i][0] + bv[i][0], 0.f);
                    acc[i][1] += fmaxf(__bfloat162float(hv1[i].y) + e1.c0 * u0[i][1] + e1.c1 * u1[i][1] + bv[i][1], 0.f);
                }
            }
        }
        if (p < p1) {
            EdgeRec e0 = pack[p];
            const __hip_bfloat16* b0 = mh + (size_t)e0.r * LDK;
            #pragma unroll
            for (int i = 0; i < 3; ++i) {
                int j = 2 * lane + 128 * i;
                if (j < 300) {
                    __hip_bfloat162 hv = *(const __hip_bfloat162*)&b0[j];
                    acc[i][0] += fmaxf(__bfloat162float(hv.x) + e0.c0 * u0[i][0] + e0.c1 * u1[i][0] + bv[i][0], 0.f);
                    acc[i][1] += fmaxf(__bfloat162float(hv.y) + e0.c0 * u0[i][1] + e0.c1 * u1[i][1] + bv[i][1], 0.f);
                }
            }
        }
        #pragma unroll
        for (int i = 0; i < 3; ++i) {
            int j = 2 * lane + 128 * i;
            if (j < 300) {
                float v0 = acc[i][0] * sc[i][0] + sh[i][0];
                float v1 = acc[i][1] * sc[i][1] + sh[i][1];
                if (do_relu) { v0 = fmaxf(v0, 0.f); v1 = fmaxf(v1, 0.f); }
                __hip_bfloat162 o;
                o.x = __float2bfloat16(v0);
                o.y = __float2bfloat16(v1);
                *(__hip_bfloat162*)&h[(size_t)n * LDK + j] = o;
            }
        }
    }
}

// ---------------- attention pool (LDS-cached h tile) -> bf16 wpool/mean [1024x320] ----------------
__global__ __launch_bounds__(320) void k_pool(const __hip_bfloat16* __restrict__ h, const float* __restrict__ qk,
                                              __hip_bfloat16* __restrict__ wpb, __hip_bfloat16* __restrict__ mnb) {
    int b = blockIdx.x;
    int tid = threadIdx.x;
    int wave = tid >> 6, lane = tid & 63;
    __shared__ float qk_s[300];
    __shared__ float sc[50];
    __shared__ __hip_bfloat16 hs[50][304];
    if (tid < 300) qk_s[tid] = qk[(size_t)b * 320 + tid];
    __syncthreads();
    for (int k = wave; k < 50; k += 5) {
        const __hip_bfloat16* hp = h + (long)(b * 50 + k) * LDK;
        float partial = 0.f;
        #pragma unroll
        for (int i = 0; i < 5; ++i) {
            int j = lane + i * 64;
            if (j < 300) {
                __hip_bfloat16 hv = hp[j];
                hs[k][j] = hv;
                partial += __bfloat162float(hv) * qk_s[j];
            }
        }
        #pragma unroll
        for (int s = 32; s > 0; s >>= 1) partial += __shfl_xor(partial, s, 64);
        if (lane == 0) sc[k] = partial * (1.f / 16.f);
    }
    __syncthreads();
    if (tid == 0) {
        float mx = sc[0];
        for (int k = 1; k < 50; ++k) mx = fmaxf(mx, sc[k]);
        float s = 0.f;
        for (int k = 0; k < 50; ++k) { float e = __expf(sc[k] - mx); sc[k] = e; s += e; }
        float inv = 1.f / s;
        for (int k = 0; k < 50; ++k) sc[k] *= inv;
    }
    __syncthreads();
    if (tid < 300) {
        float aw = 0.f, am = 0.f;
        for (int k = 0; k < 50; ++k) {
            float v = __bfloat162float(hs[k][tid]);
            aw += sc[k] * v;
            am += v;
        }
        wpb[(size_t)b * 320 + tid] = __float2bfloat16(aw);
        mnb[(size_t)b * 320 + tid] = __float2bfloat16(am * (1.f / 50.f));
    }
}

// ---------------- combine: f = relu(att) + metal2 + relu(lig + lg_b), bf16 ----------------
__global__ void k_comb(const float* __restrict__ attb, const float* __restrict__ ligb,
                       const float* __restrict__ metal2, const float* __restrict__ lg_bias,
                       __hip_bfloat16* __restrict__ fb) {
    int idx = blockIdx.x * 256 + threadIdx.x;
    if (idx >= 1000 * 256) return;
    int c = idx & 255;
    float f = fmaxf(attb[idx], 0.f) + metal2[idx] + fmaxf(ligb[idx] + lg_bias[c], 0.f);
    fb[idx] = __float2bfloat16(f);
}

// ---------------- out: softplus(a + ph1b) . ph2w + ph2b ----------------
__global__ __launch_bounds__(512) void k_out(const float* __restrict__ a2, const float* __restrict__ ph1b,
                                             const float* __restrict__ ph2w, const float* __restrict__ ph2b,
                                             float* __restrict__ out) {
    int b = blockIdx.x, t = threadIdx.x;
    int lane = t & 63, wv = t >> 6;
    float a = a2[(size_t)b * 512 + t] + ph1b[t];
    float sp = fmaxf(a, 0.f) + log1pf(__expf(-fabsf(a)));
    float r = sp * ph2w[t];
    #pragma unroll
    for (int s = 32; s > 0; s >>= 1) r += __shfl_xor(r, s, 64);
    __shared__ float red[8];
    if (lane == 0) red[wv] = r;
    __syncthreads();
    if (t == 0) {
        float s = 0.f;
        #pragma unroll
        for (int i = 0; i < 8; ++i) s += red[i];
        out[b] = s + ph2b[0];
    }
}

extern "C" void kernel_launch(void* const* d_in, const int* in_sizes, int n_in,
                              void* d_out, int out_size, void* d_ws, size_t ws_size,
                              hipStream_t stream) {
    const int*   x_type   = (const int*)d_in[0];
    const float* x_feat   = (const float*)d_in[1];
    const int*   eindex   = (const int*)d_in[2];
    const float* eattr    = (const float*)d_in[3];
    const int*   mtype    = (const int*)d_in[4];
    const float* mfeat    = (const float*)d_in[5];
    const float* x_emb    = (const float*)d_in[6];
    const float* x_weight = (const float*)d_in[7];
    const float* ew1      = (const float*)d_in[8];
    const float* mlp_w    = (const float*)d_in[9];
    const float* mlp_b    = (const float*)d_in[10];
    const float* bn_g     = (const float*)d_in[11];
    const float* bn_b     = (const float*)d_in[12];
    const float* bn_rm    = (const float*)d_in[13];
    const float* bn_rv    = (const float*)d_in[14];
    const float* me1_w    = (const float*)d_in[15];
    const float* me1_b    = (const float*)d_in[16];
    const float* me2      = (const float*)d_in[17];
    const float* wq       = (const float*)d_in[18];
    const float* wk       = (const float*)d_in[19];
    const float* wv       = (const float*)d_in[20];
    const float* ml_w     = (const float*)d_in[21];
    const float* ml_b     = (const float*)d_in[22];
    const float* lg_w     = (const float*)d_in[23];
    const float* lg_b     = (const float*)d_in[24];
    const float* ph1_w    = (const float*)d_in[25];
    const float* ph1_b    = (const float*)d_in[26];
    const float* ph2_w    = (const float*)d_in[27];
    const float* ph2_b    = (const float*)d_in[28];

    char* ws = (char*)d_ws;
    size_t o = 0;
    auto alloc = [&](size_t bytes) -> void* {
        void* p = ws + o;
        o += (bytes + 255) & ~(size_t)255;
        return p;
    };
    __hip_bfloat16* h    = (__hip_bfloat16*)alloc((size_t)MPAD * LDK * 2);
    __hip_bfloat16* mh   = (__hip_bfloat16*)alloc((size_t)MPAD * LDK * 2);
    __hip_bfloat16* wb   = (__hip_bfloat16*)alloc((size_t)5 * 320 * 320 * 2);
    int*     cnt    = (int*)alloc((size_t)NNODES * 4);
    int*     offs   = (int*)alloc((size_t)(NNODES + 1) * 4);
    int*     cur    = (int*)alloc((size_t)NNODES * 4);
    int*     bsum   = (int*)alloc((size_t)64 * 4);
    EdgeRec* pack   = (EdgeRec*)alloc((size_t)NTOT * sizeof(EdgeRec));
    float*   prm    = (float*)alloc((size_t)NLAYERS * 1520 * 4);
    float*   metal2 = (float*)alloc((size_t)1000 * 256 * 4);
    float*   qk     = (float*)alloc((size_t)1024 * 320 * 4);
    float*   me1wT  = (float*)alloc((size_t)17 * 300 * 4);
    __hip_bfloat16* mfb  = (__hip_bfloat16*)alloc((size_t)1024 * 320 * 2);
    __hip_bfloat16* wcat = (__hip_bfloat16*)alloc((size_t)512 * 320 * 2);
    __hip_bfloat16* wkTb = (__hip_bfloat16*)alloc((size_t)320 * 256 * 2);
    __hip_bfloat16* qb   = (__hip_bfloat16*)alloc((size_t)1024 * 256 * 2);
    __hip_bfloat16* xfb  = (__hip_bfloat16*)alloc((size_t)MPAD * 32 * 2);
    __hip_bfloat16* xwTb = (__hip_bfloat16*)alloc((size_t)320 * 32 * 2);
    __hip_bfloat16* wvB  = (__hip_bfloat16*)alloc((size_t)256 * 320 * 2);
    __hip_bfloat16* lgwB = (__hip_bfloat16*)alloc((size_t)256 * 320 * 2);
    __hip_bfloat16* ph1wb= (__hip_bfloat16*)alloc((size_t)512 * 256 * 2);
    __hip_bfloat16* wpb  = (__hip_bfloat16*)alloc((size_t)1024 * 320 * 2);
    __hip_bfloat16* mnb  = (__hip_bfloat16*)alloc((size_t)1024 * 320 * 2);
    float*   attb   = (float*)alloc((size_t)1024 * 256 * 4);
    float*   ligb   = (float*)alloc((size_t)1024 * 256 * 4);
    __hip_bfloat16* fb = (__hip_bfloat16*)alloc((size_t)1024 * 256 * 2);
    float*   a2     = (float*)alloc((size_t)1024 * 512 * 4);
    (void)ws_size; (void)in_sizes; (void)n_in; (void)out_size;

    hipMemsetAsync(cnt, 0, (size_t)NNODES * 4, stream);
    hipMemsetAsync(cur, 0, (size_t)NNODES * 4, stream);
    hipMemsetAsync(mfb, 0, (size_t)1024 * 320 * 2, stream);

    k_cvt<<<(5 * 320 * 320 + 255) / 256, 256, 0, stream>>>(mlp_w, wb);
    k_cvt2<<<(512 * 320 + 320 * 256 + 255) / 256, 256, 0, stream>>>(wq, ml_w, wk, wcat, wkTb);
    k_cvt3<<<(1911788 + 255) / 256, 256, 0, stream>>>(x_feat, x_weight, wv, lg_w, ph1_w, me1_w,
                                                      xfb, xwTb, wvB, lgwB, ph1wb, me1wT);
    k_initg<<<784, 256, 0, stream>>>(xfb, xwTb, x_type, x_emb, h);
    k_count<<<(NTOT + 255) / 256, 256, 0, stream>>>(eindex, cnt);
    k_scan1<<<NSCAN, 1024, 0, stream>>>(cnt, offs, bsum);
    k_scan2<<<1, 64, 0, stream>>>(bsum);
    k_scan3<<<NSCAN, 1024, 0, stream>>>(offs, bsum);
    k_fill<<<(NTOT + 255) / 256, 256, 0, stream>>>(eindex, eattr, offs, cur, pack);
    {
        dim3 gp(300, NLAYERS);
        k_prep<<<gp, 64, 0, stream>>>(mlp_w, ew1, mlp_b, bn_g, bn_b, bn_rm, bn_rv, prm);
    }
    // metal path: mf -> {q, metal2} -> qk  (batched MFMA GEMMs)
    k_mf<<<(1000 * 300 + 255) / 256, 256, 0, stream>>>(mtype, mfeat, me1wT, me1_b, me2, mfb);
    {
        dim3 g1(8, 8);   // M=1024, N=512, K=320
        k_mm<<<g1, 256, 0, stream>>>(mfb, 320, wcat, 320, 320, 0, ml_b, qb, metal2, qk);
        dim3 g2(8, 5);   // M=1024, N=320, K=256
        k_mm<<<g2, 256, 0, stream>>>(qb, 256, wkTb, 256, 256, 1, ml_b, qb, metal2, qk);
    }

    for (int l = 0; l < NLAYERS; ++l) {
        k_gemm<<<784, 256, 0, stream>>>(h, wb + (size_t)l * 102400, mh);
        int aggr_grid = (NNODES + 4 * NPW - 1) / (4 * NPW);
        k_aggr<<<aggr_grid, 256, 0, stream>>>(mh, pack, offs, prm + (size_t)l * 1520, h,
                                              (l < NLAYERS - 1) ? 1 : 0);
    }

    k_pool<<<1000, 320, 0, stream>>>(h, qk, wpb, mnb);
    {
        dim3 ga(8, 4);   // M=1024, N=256, K=320
        k_mm2<<<ga, 256, 0, stream>>>(wpb, 320, wvB, 320, 320, attb, 256);
        k_mm2<<<ga, 256, 0, stream>>>(mnb, 320, lgwB, 320, 320, ligb, 256);
        k_comb<<<(1000 * 256 + 255) / 256, 256, 0, stream>>>(attb, ligb, metal2, lg_b, fb);
        dim3 gph(8, 8);  // M=1024, N=512, K=256
        k_mm2<<<gph, 256, 0, stream>>>(fb, 256, ph1wb, 256, 256, a2, 512);
        k_out<<<1000, 512, 0, stream>>>(a2, ph1_b, ph2_w, ph2_b, (float*)d_out);
    }
}

// Round 14
// 576.352 us; speedup vs baseline: 1.0017x; 1.0017x over previous
//
#include <hip/hip_runtime.h>
#include <hip/hip_bf16.h>
#include <math.h>

#define NNODES  50000
#define NEDGES  200000
#define NTOT    250000      // E + N self loops
#define EMB     300
#define LDK     320         // padded K stride (bf16 h / mh / weights)
#define MPAD    50048       // 391 * 128 (GEMM M padding)
#define NLAYERS 5
#define NSCAN   49          // ceil(NNODES / 1024)
#define NPW     8           // nodes per wave in k_aggr (amortize prm prologue)

struct EdgeRec { int r; float c0, c1; };

typedef __attribute__((ext_vector_type(8))) short short8;
typedef __attribute__((ext_vector_type(4))) float floatx4;

__device__ inline void gll16(const void* g, void* s) {
    __builtin_amdgcn_global_load_lds((const __attribute__((address_space(1))) unsigned*)g,
                                     (__attribute__((address_space(3))) unsigned*)s, 16, 0, 0);
}

// ---------------- weight convert: wb[l][320][320] = bf16(mlp_w[l][300][300]) zero-padded ----------------
__global__ void k_cvt(const float* __restrict__ w, __hip_bfloat16* __restrict__ wb) {
    int idx = blockIdx.x * 256 + threadIdx.x;
    if (idx >= 5 * 320 * 320) return;
    int l = idx / 102400, r = idx % 102400, n = r / 320, k = r % 320;
    float v = (n < 300 && k < 300) ? w[l * 90000 + n * 300 + k] : 0.f;
    wb[idx] = __float2bfloat16(v);
}

// ---------------- metal-path weight packs: wcat[512][320] = [wq; ml_w], wkTb[320][256] = wk^T ----------------
__global__ void k_cvt2(const float* __restrict__ wq, const float* __restrict__ ml_w,
                       const float* __restrict__ wk,
                       __hip_bfloat16* __restrict__ wcat, __hip_bfloat16* __restrict__ wkTb) {
    int idx = blockIdx.x * 256 + threadIdx.x;
    if (idx < 512 * 320) {
        int r = idx / 320, k = idx % 320;
        float v = 0.f;
        if (k < 300) v = (r < 256) ? wq[r * 300 + k] : ml_w[(r - 256) * 300 + k];
        wcat[idx] = __float2bfloat16(v);
        return;
    }
    idx -= 512 * 320;
    if (idx < 320 * 256) {
        int c = idx / 256, j = idx % 256;
        float v = (c < 300) ? wk[j * 300 + c] : 0.f;
        wkTb[idx] = __float2bfloat16(v);
    }
}

// ---------------- init/head weight packs ----------------
__global__ void k_cvt3(const float* __restrict__ xf, const float* __restrict__ xw,
                       const float* __restrict__ wv, const float* __restrict__ lg_w,
                       const float* __restrict__ ph1_w, const float* __restrict__ me1_w,
                       __hip_bfloat16* __restrict__ xfb, __hip_bfloat16* __restrict__ xwTb,
                       __hip_bfloat16* __restrict__ wvB, __hip_bfloat16* __restrict__ lgwB,
                       __hip_bfloat16* __restrict__ ph1wb, float* __restrict__ me1wT) {
    int idx = blockIdx.x * 256 + threadIdx.x;
    if (idx < 1601536) {
        int n = idx >> 5, k = idx & 31;
        xfb[idx] = __float2bfloat16((n < 50000 && k < 16) ? xf[n * 16 + k] : 0.f);
        return;
    }
    idx -= 1601536;
    if (idx < 10240) {
        int n = idx >> 5, k = idx & 31;
        xwTb[idx] = __float2bfloat16((n < 300 && k < 16) ? xw[k * 300 + n] : 0.f);
        return;
    }
    idx -= 10240;
    if (idx < 81920) { int r = idx / 320, k = idx % 320;
        wvB[idx] = __float2bfloat16((k < 300) ? wv[r * 300 + k] : 0.f); return; }
    idx -= 81920;
    if (idx < 81920) { int r = idx / 320, k = idx % 320;
        lgwB[idx] = __float2bfloat16((k < 300) ? lg_w[r * 300 + k] : 0.f); return; }
    idx -= 81920;
    if (idx < 131072) { ph1wb[idx] = __float2bfloat16(ph1_w[idx]); return; }
    idx -= 131072;
    if (idx < 5100) { int r = idx / 17, c = idx % 17; me1wT[c * 300 + r] = me1_w[idx]; }
}

// ---------------- mf = me1b + me2[mt] + mfeat @ me1wT, bf16 [1024,320] (pads pre-zeroed) ----------------
__global__ __launch_bounds__(256) void k_mf(const int* __restrict__ mt, const float* __restrict__ mfeat,
                                            const float* __restrict__ me1wT, const float* __restrict__ me1b,
                                            const float* __restrict__ me2,
                                            __hip_bfloat16* __restrict__ mfb) {
    int idx = blockIdx.x * 256 + threadIdx.x;
    if (idx >= 1000 * 300) return;
    int g = idx / 300, c = idx % 300;
    float v = me1b[c] + me2[(size_t)mt[g] * 300 + c];
    #pragma unroll
    for (int k = 0; k < 17; ++k) v += mfeat[g * 17 + k] * me1wT[k * 300 + c];
    mfb[(size_t)g * 320 + c] = __float2bfloat16(v);
}

// ---------------- generic 128x64 MFMA GEMM for metal path (modes 0/1) ----------------
__global__ __launch_bounds__(256) void k_mm(const __hip_bfloat16* __restrict__ A, int lda,
                                            const __hip_bfloat16* __restrict__ B, int ldb,
                                            int K, int mode,
                                            const float* __restrict__ mlb,
                                            __hip_bfloat16* __restrict__ qb,
                                            float* __restrict__ metal2,
                                            float* __restrict__ qkout) {
    __shared__ __hip_bfloat16 As[128 * 32];
    __shared__ __hip_bfloat16 Bs[64 * 32];
    int tid = threadIdx.x, lane = tid & 63, w = tid >> 6;
    int row0 = blockIdx.x * 128, col0 = blockIdx.y * 64;

    floatx4 acc[2][4];
    #pragma unroll
    for (int i = 0; i < 2; ++i)
        #pragma unroll
        for (int j = 0; j < 4; ++j) acc[i][j] = (floatx4){0.f, 0.f, 0.f, 0.f};

    const __hip_bfloat16* ga0 = A + (size_t)(row0 + w * 32 + (lane >> 2)) * lda + (lane & 3) * 8;
    const __hip_bfloat16* ga1 = ga0 + (size_t)16 * lda;
    const __hip_bfloat16* gb  = B + (size_t)(col0 + w * 16 + (lane >> 2)) * ldb + (lane & 3) * 8;
    __hip_bfloat16* sa0 = &As[(w * 32) * 32];
    __hip_bfloat16* sa1 = &As[(w * 32 + 16) * 32];
    __hip_bfloat16* sb  = &Bs[(w * 16) * 32];

    int m15 = lane & 15, kof = (lane >> 4) * 8;

    for (int k0 = 0; k0 < K; k0 += 32) {
        __syncthreads();
        gll16(ga0 + k0, sa0);
        gll16(ga1 + k0, sa1);
        gll16(gb  + k0, sb);
        __syncthreads();

        short8 a[2], b[4];
        a[0] = *(const short8*)&As[(w * 32 +      m15) * 32 + kof];
        a[1] = *(const short8*)&As[(w * 32 + 16 + m15) * 32 + kof];
        #pragma unroll
        for (int nt = 0; nt < 4; ++nt)
            b[nt] = *(const short8*)&Bs[(nt * 16 + m15) * 32 + kof];

        #pragma unroll
        for (int mt = 0; mt < 2; ++mt)
            #pragma unroll
            for (int nt = 0; nt < 4; ++nt)
                acc[mt][nt] = __builtin_amdgcn_mfma_f32_16x16x32_bf16(a[mt], b[nt], acc[mt][nt], 0, 0, 0);
    }

    int rbase = row0 + w * 32 + (lane >> 4) * 4;
    #pragma unroll
    for (int mt = 0; mt < 2; ++mt)
        #pragma unroll
        for (int i = 0; i < 4; ++i) {
            int gr = rbase + mt * 16 + i;
            #pragma unroll
            for (int nt = 0; nt < 4; ++nt) {
                int gc = col0 + nt * 16 + m15;
                float v = acc[mt][nt][i];
                if (mode == 0) {
                    if (gc < 256) qb[(size_t)gr * 256 + gc] = __float2bfloat16(v);
                    else if (gr < 1000) metal2[(size_t)gr * 256 + (gc - 256)] = fmaxf(v + mlb[gc - 256], 0.f);
                } else {
                    if (gc < 300 && gr < 1000) qkout[(size_t)gr * 320 + gc] = v;
                }
            }
        }
}

// ---------------- generic 128x64 MFMA GEMM, raw fp32 store (head path) ----------------
__global__ __launch_bounds__(256) void k_mm2(const __hip_bfloat16* __restrict__ A, int lda,
                                             const __hip_bfloat16* __restrict__ B, int ldb,
                                             int K, float* __restrict__ C, int ldc) {
    __shared__ __hip_bfloat16 As[128 * 32];
    __shared__ __hip_bfloat16 Bs[64 * 32];
    int tid = threadIdx.x, lane = tid & 63, w = tid >> 6;
    int row0 = blockIdx.x * 128, col0 = blockIdx.y * 64;

    floatx4 acc[2][4];
    #pragma unroll
    for (int i = 0; i < 2; ++i)
        #pragma unroll
        for (int j = 0; j < 4; ++j) acc[i][j] = (floatx4){0.f, 0.f, 0.f, 0.f};

    const __hip_bfloat16* ga0 = A + (size_t)(row0 + w * 32 + (lane >> 2)) * lda + (lane & 3) * 8;
    const __hip_bfloat16* ga1 = ga0 + (size_t)16 * lda;
    const __hip_bfloat16* gb  = B + (size_t)(col0 + w * 16 + (lane >> 2)) * ldb + (lane & 3) * 8;
    __hip_bfloat16* sa0 = &As[(w * 32) * 32];
    __hip_bfloat16* sa1 = &As[(w * 32 + 16) * 32];
    __hip_bfloat16* sb  = &Bs[(w * 16) * 32];

    int m15 = lane & 15, kof = (lane >> 4) * 8;

    for (int k0 = 0; k0 < K; k0 += 32) {
        __syncthreads();
        gll16(ga0 + k0, sa0);
        gll16(ga1 + k0, sa1);
        gll16(gb  + k0, sb);
        __syncthreads();

        short8 a[2], b[4];
        a[0] = *(const short8*)&As[(w * 32 +      m15) * 32 + kof];
        a[1] = *(const short8*)&As[(w * 32 + 16 + m15) * 32 + kof];
        #pragma unroll
        for (int nt = 0; nt < 4; ++nt)
            b[nt] = *(const short8*)&Bs[(nt * 16 + m15) * 32 + kof];

        #pragma unroll
        for (int mt = 0; mt < 2; ++mt)
            #pragma unroll
            for (int nt = 0; nt < 4; ++nt)
                acc[mt][nt] = __builtin_amdgcn_mfma_f32_16x16x32_bf16(a[mt], b[nt], acc[mt][nt], 0, 0, 0);
    }

    int rbase = row0 + w * 32 + (lane >> 4) * 4;
    #pragma unroll
    for (int mt = 0; mt < 2; ++mt)
        #pragma unroll
        for (int i = 0; i < 4; ++i) {
            int gr = rbase + mt * 16 + i;
            #pragma unroll
            for (int nt = 0; nt < 4; ++nt)
                C[(size_t)gr * ldc + col0 + nt * 16 + m15] = acc[mt][nt][i];
        }
}

// ---------------- node init as MFMA GEMM: h = bf16(xemb[xt] + xfb @ xwTb^T), K=32 (one iter) ----------------
__global__ __launch_bounds__(256) void k_initg(const __hip_bfloat16* __restrict__ A,
                                               const __hip_bfloat16* __restrict__ B,
                                               const int* __restrict__ xt,
                                               const float* __restrict__ xemb,
                                               __hip_bfloat16* __restrict__ h) {
    int b = blockIdx.x;
    int rowblk = (b >> 4) * 8 + (b & 7);
    if (rowblk >= 391) return;
    int row0 = rowblk * 128;
    int col0 = ((b >> 3) & 1) * 160;

    __shared__ __hip_bfloat16 As[128 * 32];
    __shared__ __hip_bfloat16 Bs[160 * 32];
    int tid = threadIdx.x;
    int lane = tid & 63, w = tid >> 6;

    floatx4 acc[2][10];
    #pragma unroll
    for (int i = 0; i < 2; ++i)
        #pragma unroll
        for (int j = 0; j < 10; ++j) acc[i][j] = (floatx4){0.f, 0.f, 0.f, 0.f};

    const __hip_bfloat16* ga0 = A + (size_t)(row0 + w * 32 + (lane >> 2)) * 32 + (lane & 3) * 8;
    const __hip_bfloat16* ga1 = ga0 + (size_t)16 * 32;
    __hip_bfloat16* sa0 = &As[(w * 32) * 32];
    __hip_bfloat16* sa1 = &As[(w * 32 + 16) * 32];
    int brow0 = (w < 2) ? w * 48 : 96 + (w - 2) * 32;
    int nb = (w < 2) ? 3 : 2;
    const __hip_bfloat16* gb = B + (size_t)(col0 + brow0 + (lane >> 2)) * 32 + (lane & 3) * 8;
    __hip_bfloat16* sb = &Bs[brow0 * 32];

    int m15 = lane & 15, kof = (lane >> 4) * 8;

    gll16(ga0, sa0);
    gll16(ga1, sa1);
    for (int i = 0; i < nb; ++i)
        gll16(gb + (size_t)i * 16 * 32, sb + i * 16 * 32);
    __syncthreads();

    short8 a[2], bb[10];
    a[0] = *(const short8*)&As[(w * 32 +      m15) * 32 + kof];
    a[1] = *(const short8*)&As[(w * 32 + 16 + m15) * 32 + kof];
    #pragma unroll
    for (int nt = 0; nt < 10; ++nt)
        bb[nt] = *(const short8*)&Bs[(nt * 16 + m15) * 32 + kof];

    #pragma unroll
    for (int mt = 0; mt < 2; ++mt)
        #pragma unroll
        for (int nt = 0; nt < 10; ++nt)
            acc[mt][nt] = __builtin_amdgcn_mfma_f32_16x16x32_bf16(a[mt], bb[nt], acc[mt][nt], 0, 0, 0);

    int rbase = row0 + w * 32 + (lane >> 4) * 4;
    #pragma unroll
    for (int mt = 0; mt < 2; ++mt)
        #pragma unroll
        for (int i = 0; i < 4; ++i) {
            int gr = rbase + mt * 16 + i;
            if (gr < NNODES) {
                const float* er = xemb + (size_t)xt[gr] * 300;
                #pragma unroll
                for (int nt = 0; nt < 10; ++nt) {
                    int gc = col0 + nt * 16 + m15;
                    if (gc < 300)
                        h[(size_t)gr * LDK + gc] = __float2bfloat16(acc[mt][nt][i] + er[gc]);
                }
            }
        }
}

// ---------------- CSR build ----------------
__global__ void k_count(const int* __restrict__ ei, int* __restrict__ cnt) {
    int e = blockIdx.x * blockDim.x + threadIdx.x;
    if (e >= NTOT) return;
    int c = (e < NEDGES) ? ei[NEDGES + e] : (e - NEDGES);
    atomicAdd(&cnt[c], 1);
}

__global__ __launch_bounds__(1024) void k_scan1(const int* __restrict__ cnt, int* __restrict__ off,
                                                int* __restrict__ bsum) {
    int tid = threadIdx.x;
    int gid = blockIdx.x * 1024 + tid;
    int lane = tid & 63, wv = tid >> 6;
    int v = (gid < NNODES) ? cnt[gid] : 0;
    int x = v;
    #pragma unroll
    for (int s = 1; s < 64; s <<= 1) {
        int t = __shfl_up(x, s, 64);
        if (lane >= s) x += t;
    }
    __shared__ int wsum[16];
    if (lane == 63) wsum[wv] = x;
    __syncthreads();
    if (wv == 0) {
        int w = (lane < 16) ? wsum[lane] : 0;
        #pragma unroll
        for (int s = 1; s < 16; s <<= 1) {
            int t = __shfl_up(w, s, 64);
            if (lane >= s) w += t;
        }
        if (lane < 16) wsum[lane] = w;
    }
    __syncthreads();
    int base = (wv > 0) ? wsum[wv - 1] : 0;
    int incl = x + base;
    if (gid < NNODES) off[gid] = incl - v;
    if (tid == 1023) bsum[blockIdx.x] = incl;
}

__global__ __launch_bounds__(64) void k_scan2(int* __restrict__ bsum) {
    int lane = threadIdx.x;
    int v = (lane < NSCAN) ? bsum[lane] : 0;
    int x = v;
    #pragma unroll
    for (int s = 1; s < 64; s <<= 1) {
        int t = __shfl_up(x, s, 64);
        if (lane >= s) x += t;
    }
    if (lane < NSCAN) bsum[lane] = x - v;
}

__global__ __launch_bounds__(1024) void k_scan3(int* __restrict__ off, const int* __restrict__ bsum) {
    int gid = blockIdx.x * 1024 + threadIdx.x;
    if (gid < NNODES) off[gid] += bsum[blockIdx.x];
    if (gid == 0) off[NNODES] = NTOT;
}

__global__ void k_fill(const int* __restrict__ ei, const float* __restrict__ ea,
                       const int* __restrict__ off, int* __restrict__ cur,
                       EdgeRec* __restrict__ pack) {
    int e = blockIdx.x * blockDim.x + threadIdx.x;
    if (e >= NTOT) return;
    int r, c; float c0, c1;
    if (e < NEDGES) { r = ei[e]; c = ei[NEDGES + e]; c0 = ea[2 * e]; c1 = ea[2 * e + 1]; }
    else            { r = c = e - NEDGES; c0 = 0.f; c1 = 4.f; }
    int p = atomicAdd(&cur[c], 1);
    EdgeRec rec; rec.r = r; rec.c0 = c0; rec.c1 = c1;
    pack[off[c] + p] = rec;
}

// ---------------- per-layer precompute, all layers in one launch ----------------
__global__ __launch_bounds__(64) void k_prep(const float* __restrict__ mlp_w, const float* __restrict__ ew1,
                                             const float* __restrict__ mlp_b, const float* __restrict__ bn_g,
                                             const float* __restrict__ bn_b, const float* __restrict__ bn_rm,
                                             const float* __restrict__ bn_rv, float* __restrict__ prm) {
    int j = blockIdx.x, l = blockIdx.y;
    int lane = threadIdx.x;
    const float* W  = mlp_w + (size_t)l * 90000 + (size_t)j * 300;
    const float* ew = ew1 + l * 600;
    float a0 = 0.f, a1 = 0.f;
    #pragma unroll
    for (int i = 0; i < 5; ++i) {
        int k = lane + i * 64;
        if (k < 300) {
            float w = W[k];
            a0 += w * ew[k];
            a1 += w * ew[300 + k];
        }
    }
    #pragma unroll
    for (int s = 32; s > 0; s >>= 1) { a0 += __shfl_xor(a0, s, 64); a1 += __shfl_xor(a1, s, 64); }
    if (lane == 0) {
        float* p = prm + l * 1520;
        p[j] = a0;
        p[304 + j] = a1;
        p[608 + j] = mlp_b[l * 300 + j];
        float sc = bn_g[l * 300 + j] * rsqrtf(bn_rv[l * 300 + j] + 1e-5f);
        p[912 + j] = sc;
        p[1216 + j] = bn_b[l * 300 + j] - bn_rm[l * 300 + j] * sc;
    }
}

// ---------------- MFMA GEMM (layers): BK=32 LDS-staged 128x160 block, XCD-swizzled grid ----------------
__global__ __launch_bounds__(256) void k_gemm(const __hip_bfloat16* __restrict__ A,
                                              const __hip_bfloat16* __restrict__ B,
                                              __hip_bfloat16* __restrict__ C) {
    int b = blockIdx.x;
    int rowblk = (b >> 4) * 8 + (b & 7);
    if (rowblk >= 391) return;
    int row0 = rowblk * 128;
    int col0 = ((b >> 3) & 1) * 160;

    __shared__ __hip_bfloat16 As[128 * 32];
    __shared__ __hip_bfloat16 Bs[160 * 32];
    int tid = threadIdx.x;
    int lane = tid & 63, w = tid >> 6;

    floatx4 acc[2][10];
    #pragma unroll
    for (int i = 0; i < 2; ++i)
        #pragma unroll
        for (int j = 0; j < 10; ++j) acc[i][j] = (floatx4){0.f, 0.f, 0.f, 0.f};

    const __hip_bfloat16* ga0 = A + (size_t)(row0 + w * 32 + (lane >> 2)) * LDK + (lane & 3) * 8;
    const __hip_bfloat16* ga1 = ga0 + (size_t)16 * LDK;
    __hip_bfloat16* sa0 = &As[(w * 32) * 32];
    __hip_bfloat16* sa1 = &As[(w * 32 + 16) * 32];
    int brow0 = (w < 2) ? w * 48 : 96 + (w - 2) * 32;
    int nb = (w < 2) ? 3 : 2;
    const __hip_bfloat16* gb = B + (size_t)(col0 + brow0 + (lane >> 2)) * LDK + (lane & 3) * 8;
    __hip_bfloat16* sb = &Bs[brow0 * 32];

    int m15 = lane & 15, kof = (lane >> 4) * 8;

    for (int k0 = 0; k0 < LDK; k0 += 32) {
        __syncthreads();
        gll16(ga0 + k0, sa0);
        gll16(ga1 + k0, sa1);
        for (int i = 0; i < nb; ++i)
            gll16(gb + (size_t)i * 16 * LDK + k0, sb + i * 16 * 32);
        __syncthreads();

        short8 a[2], bb[10];
        a[0] = *(const short8*)&As[(w * 32 +      m15) * 32 + kof];
        a[1] = *(const short8*)&As[(w * 32 + 16 + m15) * 32 + kof];
        #pragma unroll
        for (int nt = 0; nt < 10; ++nt)
            bb[nt] = *(const short8*)&Bs[(nt * 16 + m15) * 32 + kof];

        #pragma unroll
        for (int mt = 0; mt < 2; ++mt)
            #pragma unroll
            for (int nt = 0; nt < 10; ++nt)
                acc[mt][nt] = __builtin_amdgcn_mfma_f32_16x16x32_bf16(a[mt], bb[nt], acc[mt][nt], 0, 0, 0);
    }

    int rbase = row0 + w * 32 + (lane >> 4) * 4;
    #pragma unroll
    for (int mt = 0; mt < 2; ++mt)
        #pragma unroll
        for (int i = 0; i < 4; ++i) {
            long gr = rbase + mt * 16 + i;
            #pragma unroll
            for (int nt = 0; nt < 10; ++nt)
                C[gr * LDK + col0 + nt * 16 + m15] = __float2bfloat16(acc[mt][nt][i]);
        }
}

// ---------------- aggregate: wave handles NPW sequential nodes (prm prologue amortized) ----------------
__global__ __launch_bounds__(256) void k_aggr(const __hip_bfloat16* __restrict__ mh,
                                              const EdgeRec* __restrict__ pack,
                                              const int* __restrict__ off, const float* __restrict__ prm,
                                              __hip_bfloat16* __restrict__ h, int do_relu) {
    int wave = threadIdx.x >> 6;
    int lane = threadIdx.x & 63;
    int n0 = (blockIdx.x * 4 + wave) * NPW;
    if (n0 >= NNODES) return;

    float u0[3][2], u1[3][2], bv[3][2], sc[3][2], sh[3][2];
    #pragma unroll
    for (int i = 0; i < 3; ++i) {
        int j = 2 * lane + 128 * i;
        #pragma unroll
        for (int t = 0; t < 2; ++t) {
            bool ok = (j + t) < 300;
            u0[i][t] = ok ? prm[j + t]        : 0.f;
            u1[i][t] = ok ? prm[304 + j + t]  : 0.f;
            bv[i][t] = ok ? prm[608 + j + t]  : 0.f;
            sc[i][t] = ok ? prm[912 + j + t]  : 0.f;
            sh[i][t] = ok ? prm[1216 + j + t] : 0.f;
        }
    }

    int nend = (n0 + NPW < NNODES) ? n0 + NPW : NNODES;
    for (int n = n0; n < nend; ++n) {
        float acc[3][2];
        #pragma unroll
        for (int i = 0; i < 3; ++i) { acc[i][0] = 0.f; acc[i][1] = 0.f; }
        int p0 = off[n], p1 = off[n + 1];
        int p = p0;
        for (; p + 1 < p1; p += 2) {
            EdgeRec e0 = pack[p], e1 = pack[p + 1];
            const __hip_bfloat16* b0 = mh + (size_t)e0.r * LDK;
            const __hip_bfloat16* b1 = mh + (size_t)e1.r * LDK;
            __hip_bfloat162 hv0[3], hv1[3];
            #pragma unroll
            for (int i = 0; i < 3; ++i) {
                int j = 2 * lane + 128 * i;
                if (j < 300) {
                    hv0[i] = *(const __hip_bfloat162*)&b0[j];
                    hv1[i] = *(const __hip_bfloat162*)&b1[j];
                }
            }
            #pragma unroll
            for (int i = 0; i < 3; ++i) {
                int j = 2 * lane + 128 * i;
                if (j < 300) {
                    acc[i][0] += fmaxf(__bfloat162float(hv0[i].x) + e0.c0 * u0[i][0] + e0.c1 * u1[i][0] + bv[i][0], 0.f);
                    acc[i][1] += fmaxf(__bfloat162float(hv0[i].y) + e0.c0 * u0[i][1] + e0.c1 * u1[i][1] + bv[i][1], 0.f);
                    acc[i][0] += fmaxf(__bfloat162float(hv1[i].x) + e1.c0 * u0[i][0] + e1.c1 * u1[i][0] + bv[i][0], 0.f);
                    acc[i][1] += fmaxf(__bfloat162float(hv1[i].y) + e1.c0 * u0[i][1] + e1.c1 * u1[i][1] + bv[i][1], 0.f);
                }
            }
        }
        if (p < p1) {
            EdgeRec e0 = pack[p];
            const __hip_bfloat16* b0 = mh + (size_t)e0.r * LDK;
            #pragma unroll
            for (int i = 0; i < 3; ++i) {
                int j = 2 * lane + 128 * i;
                if (j < 300) {
                    __hip_bfloat162 hv = *(const __hip_bfloat162*)&b0[j];
                    acc[i][0] += fmaxf(__bfloat162float(hv.x) + e0.c0 * u0[i][0] + e0.c1 * u1[i][0] + bv[i][0], 0.f);
                    acc[i][1] += fmaxf(__bfloat162float(hv.y) + e0.c0 * u0[i][1] + e0.c1 * u1[i][1] + bv[i][1], 0.f);
                }
            }
        }
        #pragma unroll
        for (int i = 0; i < 3; ++i) {
            int j = 2 * lane + 128 * i;
            if (j < 300) {
                float v0 = acc[i][0] * sc[i][0] + sh[i][0];
                float v1 = acc[i][1] * sc[i][1] + sh[i][1];
                if (do_relu) { v0 = fmaxf(v0, 0.f); v1 = fmaxf(v1, 0.f); }
                __hip_bfloat162 o;
                o.x = __float2bfloat16(v0);
                o.y = __float2bfloat16(v1);
                *(__hip_bfloat162*)&h[(size_t)n * LDK + j] = o;
            }
        }
    }
}

// ---------------- attention pool (LDS-cached h tile) -> bf16 wpool/mean [1024x320] ----------------
__global__ __launch_bounds__(320) void k_pool(const __hip_bfloat16* __restrict__ h, const float* __restrict__ qk,
                                              __hip_bfloat16* __restrict__ wpb, __hip_bfloat16* __restrict__ mnb) {
    int b = blockIdx.x;
    int tid = threadIdx.x;
    int wave = tid >> 6, lane = tid & 63;
    __shared__ float qk_s[300];
    __shared__ float sc[50];
    __shared__ __hip_bfloat16 hs[50][304];
    if (tid < 300) qk_s[tid] = qk[(size_t)b * 320 + tid];
    __syncthreads();
    for (int k = wave; k < 50; k += 5) {
        const __hip_bfloat16* hp = h + (long)(b * 50 + k) * LDK;
        float partial = 0.f;
        #pragma unroll
        for (int i = 0; i < 5; ++i) {
            int j = lane + i * 64;
            if (j < 300) {
                __hip_bfloat16 hv = hp[j];
                hs[k][j] = hv;
                partial += __bfloat162float(hv) * qk_s[j];
            }
        }
        #pragma unroll
        for (int s = 32; s > 0; s >>= 1) partial += __shfl_xor(partial, s, 64);
        if (lane == 0) sc[k] = partial * (1.f / 16.f);
    }
    __syncthreads();
    if (tid == 0) {
        float mx = sc[0];
        for (int k = 1; k < 50; ++k) mx = fmaxf(mx, sc[k]);
        float s = 0.f;
        for (int k = 0; k < 50; ++k) { float e = __expf(sc[k] - mx); sc[k] = e; s += e; }
        float inv = 1.f / s;
        for (int k = 0; k < 50; ++k) sc[k] *= inv;
    }
    __syncthreads();
    if (tid < 300) {
        float aw = 0.f, am = 0.f;
        for (int k = 0; k < 50; ++k) {
            float v = __bfloat162float(hs[k][tid]);
            aw += sc[k] * v;
            am += v;
        }
        wpb[(size_t)b * 320 + tid] = __float2bfloat16(aw);
        mnb[(size_t)b * 320 + tid] = __float2bfloat16(am * (1.f / 50.f));
    }
}

// ---------------- combine: f = relu(att) + metal2 + relu(lig + lg_b), bf16 ----------------
__global__ void k_comb(const float* __restrict__ attb, const float* __restrict__ ligb,
                       const float* __restrict__ metal2, const float* __restrict__ lg_bias,
                       __hip_bfloat16* __restrict__ fb) {
    int idx = blockIdx.x * 256 + threadIdx.x;
    if (idx >= 1000 * 256) return;
    int c = idx & 255;
    float f = fmaxf(attb[idx], 0.f) + metal2[idx] + fmaxf(ligb[idx] + lg_bias[c], 0.f);
    fb[idx] = __float2bfloat16(f);
}

// ---------------- out: softplus(a + ph1b) . ph2w + ph2b ----------------
__global__ __launch_bounds__(512) void k_out(const float* __restrict__ a2, const float* __restrict__ ph1b,
                                             const float* __restrict__ ph2w, const float* __restrict__ ph2b,
                                             float* __restrict__ out) {
    int b = blockIdx.x, t = threadIdx.x;
    int lane = t & 63, wv = t >> 6;
    float a = a2[(size_t)b * 512 + t] + ph1b[t];
    float sp = fmaxf(a, 0.f) + log1pf(__expf(-fabsf(a)));
    float r = sp * ph2w[t];
    #pragma unroll
    for (int s = 32; s > 0; s >>= 1) r += __shfl_xor(r, s, 64);
    __shared__ float red[8];
    if (lane == 0) red[wv] = r;
    __syncthreads();
    if (t == 0) {
        float s = 0.f;
        #pragma unroll
        for (int i = 0; i < 8; ++i) s += red[i];
        out[b] = s + ph2b[0];
    }
}

extern "C" void kernel_launch(void* const* d_in, const int* in_sizes, int n_in,
                              void* d_out, int out_size, void* d_ws, size_t ws_size,
                              hipStream_t stream) {
    const int*   x_type   = (const int*)d_in[0];
    const float* x_feat   = (const float*)d_in[1];
    const int*   eindex   = (const int*)d_in[2];
    const float* eattr    = (const float*)d_in[3];
    const int*   mtype    = (const int*)d_in[4];
    const float* mfeat    = (const float*)d_in[5];
    const float* x_emb    = (const float*)d_in[6];
    const float* x_weight = (const float*)d_in[7];
    const float* ew1      = (const float*)d_in[8];
    const float* mlp_w    = (const float*)d_in[9];
    const float* mlp_b    = (const float*)d_in[10];
    const float* bn_g     = (const float*)d_in[11];
    const float* bn_b     = (const float*)d_in[12];
    const float* bn_rm    = (const float*)d_in[13];
    const float* bn_rv    = (const float*)d_in[14];
    const float* me1_w    = (const float*)d_in[15];
    const float* me1_b    = (const float*)d_in[16];
    const float* me2      = (const float*)d_in[17];
    const float* wq       = (const float*)d_in[18];
    const float* wk       = (const float*)d_in[19];
    const float* wv       = (const float*)d_in[20];
    const float* ml_w     = (const float*)d_in[21];
    const float* ml_b     = (const float*)d_in[22];
    const float* lg_w     = (const float*)d_in[23];
    const float* lg_b     = (const float*)d_in[24];
    const float* ph1_w    = (const float*)d_in[25];
    const float* ph1_b    = (const float*)d_in[26];
    const float* ph2_w    = (const float*)d_in[27];
    const float* ph2_b    = (const float*)d_in[28];

    char* ws = (char*)d_ws;
    size_t o = 0;
    auto alloc = [&](size_t bytes) -> void* {
        void* p = ws + o;
        o += (bytes + 255) & ~(size_t)255;
        return p;
    };
    __hip_bfloat16* h    = (__hip_bfloat16*)alloc((size_t)MPAD * LDK * 2);
    __hip_bfloat16* mh   = (__hip_bfloat16*)alloc((size_t)MPAD * LDK * 2);
    __hip_bfloat16* wb   = (__hip_bfloat16*)alloc((size_t)5 * 320 * 320 * 2);
    int*     cnt    = (int*)alloc((size_t)NNODES * 4);
    int*     offs   = (int*)alloc((size_t)(NNODES + 1) * 4);
    int*     cur    = (int*)alloc((size_t)NNODES * 4);
    int*     bsum   = (int*)alloc((size_t)64 * 4);
    EdgeRec* pack   = (EdgeRec*)alloc((size_t)NTOT * sizeof(EdgeRec));
    float*   prm    = (float*)alloc((size_t)NLAYERS * 1520 * 4);
    float*   metal2 = (float*)alloc((size_t)1000 * 256 * 4);
    float*   qk     = (float*)alloc((size_t)1024 * 320 * 4);
    float*   me1wT  = (float*)alloc((size_t)17 * 300 * 4);
    __hip_bfloat16* mfb  = (__hip_bfloat16*)alloc((size_t)1024 * 320 * 2);
    __hip_bfloat16* wcat = (__hip_bfloat16*)alloc((size_t)512 * 320 * 2);
    __hip_bfloat16* wkTb = (__hip_bfloat16*)alloc((size_t)320 * 256 * 2);
    __hip_bfloat16* qb   = (__hip_bfloat16*)alloc((size_t)1024 * 256 * 2);
    __hip_bfloat16* xfb  = (__hip_bfloat16*)alloc((size_t)MPAD * 32 * 2);
    __hip_bfloat16* xwTb = (__hip_bfloat16*)alloc((size_t)320 * 32 * 2);
    __hip_bfloat16* wvB  = (__hip_bfloat16*)alloc((size_t)256 * 320 * 2);
    __hip_bfloat16* lgwB = (__hip_bfloat16*)alloc((size_t)256 * 320 * 2);
    __hip_bfloat16* ph1wb= (__hip_bfloat16*)alloc((size_t)512 * 256 * 2);
    __hip_bfloat16* wpb  = (__hip_bfloat16*)alloc((size_t)1024 * 320 * 2);
    __hip_bfloat16* mnb  = (__hip_bfloat16*)alloc((size_t)1024 * 320 * 2);
    float*   attb   = (float*)alloc((size_t)1024 * 256 * 4);
    float*   ligb   = (float*)alloc((size_t)1024 * 256 * 4);
    __hip_bfloat16* fb = (__hip_bfloat16*)alloc((size_t)1024 * 256 * 2);
    float*   a2     = (float*)alloc((size_t)1024 * 512 * 4);
    (void)ws_size; (void)in_sizes; (void)n_in; (void)out_size;

    hipMemsetAsync(cnt, 0, (size_t)NNODES * 4, stream);
    hipMemsetAsync(cur, 0, (size_t)NNODES * 4, stream);
    hipMemsetAsync(mfb, 0, (size_t)1024 * 320 * 2, stream);

    k_cvt<<<(5 * 320 * 320 + 255) / 256, 256, 0, stream>>>(mlp_w, wb);
    k_cvt2<<<(512 * 320 + 320 * 256 + 255) / 256, 256, 0, stream>>>(wq, ml_w, wk, wcat, wkTb);
    k_cvt3<<<(1911788 + 255) / 256, 256, 0, stream>>>(x_feat, x_weight, wv, lg_w, ph1_w, me1_w,
                                                      xfb, xwTb, wvB, lgwB, ph1wb, me1wT);
    k_initg<<<784, 256, 0, stream>>>(xfb, xwTb, x_type, x_emb, h);
    k_count<<<(NTOT + 255) / 256, 256, 0, stream>>>(eindex, cnt);
    k_scan1<<<NSCAN, 1024, 0, stream>>>(cnt, offs, bsum);
    k_scan2<<<1, 64, 0, stream>>>(bsum);
    k_scan3<<<NSCAN, 1024, 0, stream>>>(offs, bsum);
    k_fill<<<(NTOT + 255) / 256, 256, 0, stream>>>(eindex, eattr, offs, cur, pack);
    {
        dim3 gp(300, NLAYERS);
        k_prep<<<gp, 64, 0, stream>>>(mlp_w, ew1, mlp_b, bn_g, bn_b, bn_rm, bn_rv, prm);
    }
    // metal path: mf -> {q, metal2} -> qk  (batched MFMA GEMMs)
    k_mf<<<(1000 * 300 + 255) / 256, 256, 0, stream>>>(mtype, mfeat, me1wT, me1_b, me2, mfb);
    {
        dim3 g1(8, 8);   // M=1024, N=512, K=320
        k_mm<<<g1, 256, 0, stream>>>(mfb, 320, wcat, 320, 320, 0, ml_b, qb, metal2, qk);
        dim3 g2(8, 5);   // M=1024, N=320, K=256
        k_mm<<<g2, 256, 0, stream>>>(qb, 256, wkTb, 256, 256, 1, ml_b, qb, metal2, qk);
    }

    for (int l = 0; l < NLAYERS; ++l) {
        k_gemm<<<784, 256, 0, stream>>>(h, wb + (size_t)l * 102400, mh);
        int aggr_grid = (NNODES + 4 * NPW - 1) / (4 * NPW);
        k_aggr<<<aggr_grid, 256, 0, stream>>>(mh, pack, offs, prm + (size_t)l * 1520, h,
                                              (l < NLAYERS - 1) ? 1 : 0);
    }

    k_pool<<<1000, 320, 0, stream>>>(h, qk, wpb, mnb);
    {
        dim3 ga(8, 4);   // M=1024, N=256, K=320
        k_mm2<<<ga, 256, 0, stream>>>(wpb, 320, wvB, 320, 320, attb, 256);
        k_mm2<<<ga, 256, 0, stream>>>(mnb, 320, lgwB, 320, 320, ligb, 256);
        k_comb<<<(1000 * 256 + 255) / 256, 256, 0, stream>>>(attb, ligb, metal2, lg_b, fb);
        dim3 gph(8, 8);  // M=1024, N=512, K=256
        k_mm2<<<gph, 256, 0, stream>>>(fb, 256, ph1wb, 256, 256, a2, 512);
        k_out<<<1000, 512, 0, stream>>>(a2, ph1_b, ph2_w, ph2_b, (float*)d_out);
    }
}

// Round 15
// 564.271 us; speedup vs baseline: 1.0232x; 1.0214x over previous
//
#include <hip/hip_runtime.h>
#include <hip/hip_bf16.h>
#include <math.h>

#define NNODES  50000
#define NEDGES  200000
#define NTOT    250000      // E + N self loops
#define EMB     300
#define LDK     320         // padded K stride (bf16 h / mh / weights)
#define MPAD    50048       // 391 * 128 (GEMM M padding)
#define NLAYERS 5
#define NSCAN   49          // ceil(NNODES / 1024)
#define NPW     8           // nodes per wave in k_aggr (amortize prm prologue)

struct EdgeRec { int r; float c0, c1; };

typedef __attribute__((ext_vector_type(8))) short short8;
typedef __attribute__((ext_vector_type(4))) float floatx4;
typedef __attribute__((ext_vector_type(2))) float floatx2;

__device__ inline void gll16(const void* g, void* s) {
    __builtin_amdgcn_global_load_lds((const __attribute__((address_space(1))) unsigned*)g,
                                     (__attribute__((address_space(3))) unsigned*)s, 16, 0, 0);
}

// bf16x2 (packed in u32) -> float2 via bit ops (no cvt instructions)
__device__ inline floatx2 bf2f(unsigned u) {
    floatx2 r;
    r.x = __uint_as_float(u << 16);
    r.y = __uint_as_float(u & 0xffff0000u);
    return r;
}

// ---------------- weight convert: wb[l][320][320] = bf16(mlp_w[l][300][300]) zero-padded ----------------
__global__ void k_cvt(const float* __restrict__ w, __hip_bfloat16* __restrict__ wb) {
    int idx = blockIdx.x * 256 + threadIdx.x;
    if (idx >= 5 * 320 * 320) return;
    int l = idx / 102400, r = idx % 102400, n = r / 320, k = r % 320;
    float v = (n < 300 && k < 300) ? w[l * 90000 + n * 300 + k] : 0.f;
    wb[idx] = __float2bfloat16(v);
}

// ---------------- metal-path weight packs: wcat[512][320] = [wq; ml_w], wkTb[320][256] = wk^T ----------------
__global__ void k_cvt2(const float* __restrict__ wq, const float* __restrict__ ml_w,
                       const float* __restrict__ wk,
                       __hip_bfloat16* __restrict__ wcat, __hip_bfloat16* __restrict__ wkTb) {
    int idx = blockIdx.x * 256 + threadIdx.x;
    if (idx < 512 * 320) {
        int r = idx / 320, k = idx % 320;
        float v = 0.f;
        if (k < 300) v = (r < 256) ? wq[r * 300 + k] : ml_w[(r - 256) * 300 + k];
        wcat[idx] = __float2bfloat16(v);
        return;
    }
    idx -= 512 * 320;
    if (idx < 320 * 256) {
        int c = idx / 256, j = idx % 256;
        float v = (c < 300) ? wk[j * 300 + c] : 0.f;
        wkTb[idx] = __float2bfloat16(v);
    }
}

// ---------------- init/head weight packs ----------------
__global__ void k_cvt3(const float* __restrict__ xf, const float* __restrict__ xw,
                       const float* __restrict__ wv, const float* __restrict__ lg_w,
                       const float* __restrict__ ph1_w, const float* __restrict__ me1_w,
                       __hip_bfloat16* __restrict__ xfb, __hip_bfloat16* __restrict__ xwTb,
                       __hip_bfloat16* __restrict__ wvB, __hip_bfloat16* __restrict__ lgwB,
                       __hip_bfloat16* __restrict__ ph1wb, float* __restrict__ me1wT) {
    int idx = blockIdx.x * 256 + threadIdx.x;
    if (idx < 1601536) {
        int n = idx >> 5, k = idx & 31;
        xfb[idx] = __float2bfloat16((n < 50000 && k < 16) ? xf[n * 16 + k] : 0.f);
        return;
    }
    idx -= 1601536;
    if (idx < 10240) {
        int n = idx >> 5, k = idx & 31;
        xwTb[idx] = __float2bfloat16((n < 300 && k < 16) ? xw[k * 300 + n] : 0.f);
        return;
    }
    idx -= 10240;
    if (idx < 81920) { int r = idx / 320, k = idx % 320;
        wvB[idx] = __float2bfloat16((k < 300) ? wv[r * 300 + k] : 0.f); return; }
    idx -= 81920;
    if (idx < 81920) { int r = idx / 320, k = idx % 320;
        lgwB[idx] = __float2bfloat16((k < 300) ? lg_w[r * 300 + k] : 0.f); return; }
    idx -= 81920;
    if (idx < 131072) { ph1wb[idx] = __float2bfloat16(ph1_w[idx]); return; }
    idx -= 131072;
    if (idx < 5100) { int r = idx / 17, c = idx % 17; me1wT[c * 300 + r] = me1_w[idx]; }
}

// ---------------- mf = me1b + me2[mt] + mfeat @ me1wT, bf16 [1024,320] (pads pre-zeroed) ----------------
__global__ __launch_bounds__(256) void k_mf(const int* __restrict__ mt, const float* __restrict__ mfeat,
                                            const float* __restrict__ me1wT, const float* __restrict__ me1b,
                                            const float* __restrict__ me2,
                                            __hip_bfloat16* __restrict__ mfb) {
    int idx = blockIdx.x * 256 + threadIdx.x;
    if (idx >= 1000 * 300) return;
    int g = idx / 300, c = idx % 300;
    float v = me1b[c] + me2[(size_t)mt[g] * 300 + c];
    #pragma unroll
    for (int k = 0; k < 17; ++k) v += mfeat[g * 17 + k] * me1wT[k * 300 + c];
    mfb[(size_t)g * 320 + c] = __float2bfloat16(v);
}

// ---------------- generic 128x64 MFMA GEMM for metal path (modes 0/1) ----------------
__global__ __launch_bounds__(256) void k_mm(const __hip_bfloat16* __restrict__ A, int lda,
                                            const __hip_bfloat16* __restrict__ B, int ldb,
                                            int K, int mode,
                                            const float* __restrict__ mlb,
                                            __hip_bfloat16* __restrict__ qb,
                                            float* __restrict__ metal2,
                                            float* __restrict__ qkout) {
    __shared__ __hip_bfloat16 As[128 * 32];
    __shared__ __hip_bfloat16 Bs[64 * 32];
    int tid = threadIdx.x, lane = tid & 63, w = tid >> 6;
    int row0 = blockIdx.x * 128, col0 = blockIdx.y * 64;

    floatx4 acc[2][4];
    #pragma unroll
    for (int i = 0; i < 2; ++i)
        #pragma unroll
        for (int j = 0; j < 4; ++j) acc[i][j] = (floatx4){0.f, 0.f, 0.f, 0.f};

    const __hip_bfloat16* ga0 = A + (size_t)(row0 + w * 32 + (lane >> 2)) * lda + (lane & 3) * 8;
    const __hip_bfloat16* ga1 = ga0 + (size_t)16 * lda;
    const __hip_bfloat16* gb  = B + (size_t)(col0 + w * 16 + (lane >> 2)) * ldb + (lane & 3) * 8;
    __hip_bfloat16* sa0 = &As[(w * 32) * 32];
    __hip_bfloat16* sa1 = &As[(w * 32 + 16) * 32];
    __hip_bfloat16* sb  = &Bs[(w * 16) * 32];

    int m15 = lane & 15, kof = (lane >> 4) * 8;

    for (int k0 = 0; k0 < K; k0 += 32) {
        __syncthreads();
        gll16(ga0 + k0, sa0);
        gll16(ga1 + k0, sa1);
        gll16(gb  + k0, sb);
        __syncthreads();

        short8 a[2], b[4];
        a[0] = *(const short8*)&As[(w * 32 +      m15) * 32 + kof];
        a[1] = *(const short8*)&As[(w * 32 + 16 + m15) * 32 + kof];
        #pragma unroll
        for (int nt = 0; nt < 4; ++nt)
            b[nt] = *(const short8*)&Bs[(nt * 16 + m15) * 32 + kof];

        #pragma unroll
        for (int mt = 0; mt < 2; ++mt)
            #pragma unroll
            for (int nt = 0; nt < 4; ++nt)
                acc[mt][nt] = __builtin_amdgcn_mfma_f32_16x16x32_bf16(a[mt], b[nt], acc[mt][nt], 0, 0, 0);
    }

    int rbase = row0 + w * 32 + (lane >> 4) * 4;
    #pragma unroll
    for (int mt = 0; mt < 2; ++mt)
        #pragma unroll
        for (int i = 0; i < 4; ++i) {
            int gr = rbase + mt * 16 + i;
            #pragma unroll
            for (int nt = 0; nt < 4; ++nt) {
                int gc = col0 + nt * 16 + m15;
                float v = acc[mt][nt][i];
                if (mode == 0) {
                    if (gc < 256) qb[(size_t)gr * 256 + gc] = __float2bfloat16(v);
                    else if (gr < 1000) metal2[(size_t)gr * 256 + (gc - 256)] = fmaxf(v + mlb[gc - 256], 0.f);
                } else {
                    if (gc < 300 && gr < 1000) qkout[(size_t)gr * 320 + gc] = v;
                }
            }
        }
}

// ---------------- generic 128x64 MFMA GEMM, raw fp32 store (head path) ----------------
__global__ __launch_bounds__(256) void k_mm2(const __hip_bfloat16* __restrict__ A, int lda,
                                             const __hip_bfloat16* __restrict__ B, int ldb,
                                             int K, float* __restrict__ C, int ldc) {
    __shared__ __hip_bfloat16 As[128 * 32];
    __shared__ __hip_bfloat16 Bs[64 * 32];
    int tid = threadIdx.x, lane = tid & 63, w = tid >> 6;
    int row0 = blockIdx.x * 128, col0 = blockIdx.y * 64;

    floatx4 acc[2][4];
    #pragma unroll
    for (int i = 0; i < 2; ++i)
        #pragma unroll
        for (int j = 0; j < 4; ++j) acc[i][j] = (floatx4){0.f, 0.f, 0.f, 0.f};

    const __hip_bfloat16* ga0 = A + (size_t)(row0 + w * 32 + (lane >> 2)) * lda + (lane & 3) * 8;
    const __hip_bfloat16* ga1 = ga0 + (size_t)16 * lda;
    const __hip_bfloat16* gb  = B + (size_t)(col0 + w * 16 + (lane >> 2)) * ldb + (lane & 3) * 8;
    __hip_bfloat16* sa0 = &As[(w * 32) * 32];
    __hip_bfloat16* sa1 = &As[(w * 32 + 16) * 32];
    __hip_bfloat16* sb  = &Bs[(w * 16) * 32];

    int m15 = lane & 15, kof = (lane >> 4) * 8;

    for (int k0 = 0; k0 < K; k0 += 32) {
        __syncthreads();
        gll16(ga0 + k0, sa0);
        gll16(ga1 + k0, sa1);
        gll16(gb  + k0, sb);
        __syncthreads();

        short8 a[2], b[4];
        a[0] = *(const short8*)&As[(w * 32 +      m15) * 32 + kof];
        a[1] = *(const short8*)&As[(w * 32 + 16 + m15) * 32 + kof];
        #pragma unroll
        for (int nt = 0; nt < 4; ++nt)
            b[nt] = *(const short8*)&Bs[(nt * 16 + m15) * 32 + kof];

        #pragma unroll
        for (int mt = 0; mt < 2; ++mt)
            #pragma unroll
            for (int nt = 0; nt < 4; ++nt)
                acc[mt][nt] = __builtin_amdgcn_mfma_f32_16x16x32_bf16(a[mt], b[nt], acc[mt][nt], 0, 0, 0);
    }

    int rbase = row0 + w * 32 + (lane >> 4) * 4;
    #pragma unroll
    for (int mt = 0; mt < 2; ++mt)
        #pragma unroll
        for (int i = 0; i < 4; ++i) {
            int gr = rbase + mt * 16 + i;
            #pragma unroll
            for (int nt = 0; nt < 4; ++nt)
                C[(size_t)gr * ldc + col0 + nt * 16 + m15] = acc[mt][nt][i];
        }
}

// ---------------- node init as MFMA GEMM: h = bf16(xemb[xt] + xfb @ xwTb^T), K=32 (one iter) ----------------
__global__ __launch_bounds__(256) void k_initg(const __hip_bfloat16* __restrict__ A,
                                               const __hip_bfloat16* __restrict__ B,
                                               const int* __restrict__ xt,
                                               const float* __restrict__ xemb,
                                               __hip_bfloat16* __restrict__ h) {
    int b = blockIdx.x;
    int rowblk = (b >> 4) * 8 + (b & 7);
    if (rowblk >= 391) return;
    int row0 = rowblk * 128;
    int col0 = ((b >> 3) & 1) * 160;

    __shared__ __hip_bfloat16 As[128 * 32];
    __shared__ __hip_bfloat16 Bs[160 * 32];
    int tid = threadIdx.x;
    int lane = tid & 63, w = tid >> 6;

    floatx4 acc[2][10];
    #pragma unroll
    for (int i = 0; i < 2; ++i)
        #pragma unroll
        for (int j = 0; j < 10; ++j) acc[i][j] = (floatx4){0.f, 0.f, 0.f, 0.f};

    const __hip_bfloat16* ga0 = A + (size_t)(row0 + w * 32 + (lane >> 2)) * 32 + (lane & 3) * 8;
    const __hip_bfloat16* ga1 = ga0 + (size_t)16 * 32;
    __hip_bfloat16* sa0 = &As[(w * 32) * 32];
    __hip_bfloat16* sa1 = &As[(w * 32 + 16) * 32];
    int brow0 = (w < 2) ? w * 48 : 96 + (w - 2) * 32;
    int nb = (w < 2) ? 3 : 2;
    const __hip_bfloat16* gb = B + (size_t)(col0 + brow0 + (lane >> 2)) * 32 + (lane & 3) * 8;
    __hip_bfloat16* sb = &Bs[brow0 * 32];

    int m15 = lane & 15, kof = (lane >> 4) * 8;

    gll16(ga0, sa0);
    gll16(ga1, sa1);
    for (int i = 0; i < nb; ++i)
        gll16(gb + (size_t)i * 16 * 32, sb + i * 16 * 32);
    __syncthreads();

    short8 a[2], bb[10];
    a[0] = *(const short8*)&As[(w * 32 +      m15) * 32 + kof];
    a[1] = *(const short8*)&As[(w * 32 + 16 + m15) * 32 + kof];
    #pragma unroll
    for (int nt = 0; nt < 10; ++nt)
        bb[nt] = *(const short8*)&Bs[(nt * 16 + m15) * 32 + kof];

    #pragma unroll
    for (int mt = 0; mt < 2; ++mt)
        #pragma unroll
        for (int nt = 0; nt < 10; ++nt)
            acc[mt][nt] = __builtin_amdgcn_mfma_f32_16x16x32_bf16(a[mt], bb[nt], acc[mt][nt], 0, 0, 0);

    int rbase = row0 + w * 32 + (lane >> 4) * 4;
    #pragma unroll
    for (int mt = 0; mt < 2; ++mt)
        #pragma unroll
        for (int i = 0; i < 4; ++i) {
            int gr = rbase + mt * 16 + i;
            if (gr < NNODES) {
                const float* er = xemb + (size_t)xt[gr] * 300;
                #pragma unroll
                for (int nt = 0; nt < 10; ++nt) {
                    int gc = col0 + nt * 16 + m15;
                    if (gc < 300)
                        h[(size_t)gr * LDK + gc] = __float2bfloat16(acc[mt][nt][i] + er[gc]);
                }
            }
        }
}

// ---------------- CSR build ----------------
__global__ void k_count(const int* __restrict__ ei, int* __restrict__ cnt) {
    int e = blockIdx.x * blockDim.x + threadIdx.x;
    if (e >= NTOT) return;
    int c = (e < NEDGES) ? ei[NEDGES + e] : (e - NEDGES);
    atomicAdd(&cnt[c], 1);
}

__global__ __launch_bounds__(1024) void k_scan1(const int* __restrict__ cnt, int* __restrict__ off,
                                                int* __restrict__ bsum) {
    int tid = threadIdx.x;
    int gid = blockIdx.x * 1024 + tid;
    int lane = tid & 63, wv = tid >> 6;
    int v = (gid < NNODES) ? cnt[gid] : 0;
    int x = v;
    #pragma unroll
    for (int s = 1; s < 64; s <<= 1) {
        int t = __shfl_up(x, s, 64);
        if (lane >= s) x += t;
    }
    __shared__ int wsum[16];
    if (lane == 63) wsum[wv] = x;
    __syncthreads();
    if (wv == 0) {
        int w = (lane < 16) ? wsum[lane] : 0;
        #pragma unroll
        for (int s = 1; s < 16; s <<= 1) {
            int t = __shfl_up(w, s, 64);
            if (lane >= s) w += t;
        }
        if (lane < 16) wsum[lane] = w;
    }
    __syncthreads();
    int base = (wv > 0) ? wsum[wv - 1] : 0;
    int incl = x + base;
    if (gid < NNODES) off[gid] = incl - v;
    if (tid == 1023) bsum[blockIdx.x] = incl;
}

__global__ __launch_bounds__(64) void k_scan2(int* __restrict__ bsum) {
    int lane = threadIdx.x;
    int v = (lane < NSCAN) ? bsum[lane] : 0;
    int x = v;
    #pragma unroll
    for (int s = 1; s < 64; s <<= 1) {
        int t = __shfl_up(x, s, 64);
        if (lane >= s) x += t;
    }
    if (lane < NSCAN) bsum[lane] = x - v;
}

__global__ __launch_bounds__(1024) void k_scan3(int* __restrict__ off, const int* __restrict__ bsum) {
    int gid = blockIdx.x * 1024 + threadIdx.x;
    if (gid < NNODES) off[gid] += bsum[blockIdx.x];
    if (gid == 0) off[NNODES] = NTOT;
}

__global__ void k_fill(const int* __restrict__ ei, const float* __restrict__ ea,
                       const int* __restrict__ off, int* __restrict__ cur,
                       EdgeRec* __restrict__ pack) {
    int e = blockIdx.x * blockDim.x + threadIdx.x;
    if (e >= NTOT) return;
    int r, c; float c0, c1;
    if (e < NEDGES) { r = ei[e]; c = ei[NEDGES + e]; c0 = ea[2 * e]; c1 = ea[2 * e + 1]; }
    else            { r = c = e - NEDGES; c0 = 0.f; c1 = 4.f; }
    int p = atomicAdd(&cur[c], 1);
    EdgeRec rec; rec.r = r; rec.c0 = c0; rec.c1 = c1;
    pack[off[c] + p] = rec;
}

// ---------------- per-layer precompute, all layers in one launch ----------------
__global__ __launch_bounds__(64) void k_prep(const float* __restrict__ mlp_w, const float* __restrict__ ew1,
                                             const float* __restrict__ mlp_b, const float* __restrict__ bn_g,
                                             const float* __restrict__ bn_b, const float* __restrict__ bn_rm,
                                             const float* __restrict__ bn_rv, float* __restrict__ prm) {
    int j = blockIdx.x, l = blockIdx.y;
    int lane = threadIdx.x;
    const float* W  = mlp_w + (size_t)l * 90000 + (size_t)j * 300;
    const float* ew = ew1 + l * 600;
    float a0 = 0.f, a1 = 0.f;
    #pragma unroll
    for (int i = 0; i < 5; ++i) {
        int k = lane + i * 64;
        if (k < 300) {
            float w = W[k];
            a0 += w * ew[k];
            a1 += w * ew[300 + k];
        }
    }
    #pragma unroll
    for (int s = 32; s > 0; s >>= 1) { a0 += __shfl_xor(a0, s, 64); a1 += __shfl_xor(a1, s, 64); }
    if (lane == 0) {
        float* p = prm + l * 1520;
        p[j] = a0;
        p[304 + j] = a1;
        p[608 + j] = mlp_b[l * 300 + j];
        float sc = bn_g[l * 300 + j] * rsqrtf(bn_rv[l * 300 + j] + 1e-5f);
        p[912 + j] = sc;
        p[1216 + j] = bn_b[l * 300 + j] - bn_rm[l * 300 + j] * sc;
    }
}

// ---------------- MFMA GEMM (layers): BK=32 LDS-staged 128x160 block, XCD-swizzled grid ----------------
__global__ __launch_bounds__(256) void k_gemm(const __hip_bfloat16* __restrict__ A,
                                              const __hip_bfloat16* __restrict__ B,
                                              __hip_bfloat16* __restrict__ C) {
    int b = blockIdx.x;
    int rowblk = (b >> 4) * 8 + (b & 7);
    if (rowblk >= 391) return;
    int row0 = rowblk * 128;
    int col0 = ((b >> 3) & 1) * 160;

    __shared__ __hip_bfloat16 As[128 * 32];
    __shared__ __hip_bfloat16 Bs[160 * 32];
    int tid = threadIdx.x;
    int lane = tid & 63, w = tid >> 6;

    floatx4 acc[2][10];
    #pragma unroll
    for (int i = 0; i < 2; ++i)
        #pragma unroll
        for (int j = 0; j < 10; ++j) acc[i][j] = (floatx4){0.f, 0.f, 0.f, 0.f};

    const __hip_bfloat16* ga0 = A + (size_t)(row0 + w * 32 + (lane >> 2)) * LDK + (lane & 3) * 8;
    const __hip_bfloat16* ga1 = ga0 + (size_t)16 * LDK;
    __hip_bfloat16* sa0 = &As[(w * 32) * 32];
    __hip_bfloat16* sa1 = &As[(w * 32 + 16) * 32];
    int brow0 = (w < 2) ? w * 48 : 96 + (w - 2) * 32;
    int nb = (w < 2) ? 3 : 2;
    const __hip_bfloat16* gb = B + (size_t)(col0 + brow0 + (lane >> 2)) * LDK + (lane & 3) * 8;
    __hip_bfloat16* sb = &Bs[brow0 * 32];

    int m15 = lane & 15, kof = (lane >> 4) * 8;

    for (int k0 = 0; k0 < LDK; k0 += 32) {
        __syncthreads();
        gll16(ga0 + k0, sa0);
        gll16(ga1 + k0, sa1);
        for (int i = 0; i < nb; ++i)
            gll16(gb + (size_t)i * 16 * LDK + k0, sb + i * 16 * 32);
        __syncthreads();

        short8 a[2], bb[10];
        a[0] = *(const short8*)&As[(w * 32 +      m15) * 32 + kof];
        a[1] = *(const short8*)&As[(w * 32 + 16 + m15) * 32 + kof];
        #pragma unroll
        for (int nt = 0; nt < 10; ++nt)
            bb[nt] = *(const short8*)&Bs[(nt * 16 + m15) * 32 + kof];

        #pragma unroll
        for (int mt = 0; mt < 2; ++mt)
            #pragma unroll
            for (int nt = 0; nt < 10; ++nt)
                acc[mt][nt] = __builtin_amdgcn_mfma_f32_16x16x32_bf16(a[mt], bb[nt], acc[mt][nt], 0, 0, 0);
    }

    int rbase = row0 + w * 32 + (lane >> 4) * 4;
    #pragma unroll
    for (int mt = 0; mt < 2; ++mt)
        #pragma unroll
        for (int i = 0; i < 4; ++i) {
            long gr = rbase + mt * 16 + i;
            #pragma unroll
            for (int nt = 0; nt < 10; ++nt)
                C[gr * LDK + col0 + nt * 16 + m15] = __float2bfloat16(acc[mt][nt][i]);
        }
}

// ---------------- aggregate: packed-fp32 math (v_pk_*), wave handles NPW nodes ----------------
__global__ __launch_bounds__(256) void k_aggr(const __hip_bfloat16* __restrict__ mh,
                                              const EdgeRec* __restrict__ pack,
                                              const int* __restrict__ off, const float* __restrict__ prm,
                                              __hip_bfloat16* __restrict__ h, int do_relu) {
    int wave = threadIdx.x >> 6;
    int lane = threadIdx.x & 63;
    int n0 = (blockIdx.x * 4 + wave) * NPW;
    if (n0 >= NNODES) return;

    const floatx2 zero2 = {0.f, 0.f};
    floatx2 u0[3], u1[3], bv[3], sc[3], sh[3];
    #pragma unroll
    for (int i = 0; i < 3; ++i) {
        int j = 2 * lane + 128 * i;
        #pragma unroll
        for (int t = 0; t < 2; ++t) {
            bool ok = (j + t) < 300;
            u0[i][t] = ok ? prm[j + t]        : 0.f;
            u1[i][t] = ok ? prm[304 + j + t]  : 0.f;
            bv[i][t] = ok ? prm[608 + j + t]  : 0.f;
            sc[i][t] = ok ? prm[912 + j + t]  : 0.f;
            sh[i][t] = ok ? prm[1216 + j + t] : 0.f;
        }
    }

    int nend = (n0 + NPW < NNODES) ? n0 + NPW : NNODES;
    for (int n = n0; n < nend; ++n) {
        floatx2 acc[3];
        #pragma unroll
        for (int i = 0; i < 3; ++i) acc[i] = zero2;
        int p0 = off[n], p1 = off[n + 1];
        int p = p0;
        for (; p + 1 < p1; p += 2) {
            EdgeRec e0 = pack[p], e1 = pack[p + 1];
            const unsigned* b0 = (const unsigned*)(mh + (size_t)e0.r * LDK);
            const unsigned* b1 = (const unsigned*)(mh + (size_t)e1.r * LDK);
            unsigned raw0[3], raw1[3];
            #pragma unroll
            for (int i = 0; i < 3; ++i) {
                int j = 2 * lane + 128 * i;
                if (j < 300) {
                    raw0[i] = b0[lane + 64 * i];
                    raw1[i] = b1[lane + 64 * i];
                }
            }
            #pragma unroll
            for (int i = 0; i < 3; ++i) {
                int j = 2 * lane + 128 * i;
                if (j < 300) {
                    floatx2 t0 = e0.c0 * u0[i] + e0.c1 * u1[i] + bv[i];
                    floatx2 t1 = e1.c0 * u0[i] + e1.c1 * u1[i] + bv[i];
                    acc[i] += __builtin_elementwise_max(bf2f(raw0[i]) + t0, zero2);
                    acc[i] += __builtin_elementwise_max(bf2f(raw1[i]) + t1, zero2);
                }
            }
        }
        if (p < p1) {
            EdgeRec e0 = pack[p];
            const unsigned* b0 = (const unsigned*)(mh + (size_t)e0.r * LDK);
            #pragma unroll
            for (int i = 0; i < 3; ++i) {
                int j = 2 * lane + 128 * i;
                if (j < 300) {
                    floatx2 t0 = e0.c0 * u0[i] + e0.c1 * u1[i] + bv[i];
                    acc[i] += __builtin_elementwise_max(bf2f(b0[lane + 64 * i]) + t0, zero2);
                }
            }
        }
        #pragma unroll
        for (int i = 0; i < 3; ++i) {
            int j = 2 * lane + 128 * i;
            if (j < 300) {
                floatx2 v = acc[i] * sc[i] + sh[i];
                if (do_relu) v = __builtin_elementwise_max(v, zero2);
                __hip_bfloat162 o;
                o.x = __float2bfloat16(v.x);
                o.y = __float2bfloat16(v.y);
                *(__hip_bfloat162*)&h[(size_t)n * LDK + j] = o;
            }
        }
    }
}

// ---------------- attention pool (LDS-cached h tile) -> bf16 wpool/mean [1024x320] ----------------
__global__ __launch_bounds__(320) void k_pool(const __hip_bfloat16* __restrict__ h, const float* __restrict__ qk,
                                              __hip_bfloat16* __restrict__ wpb, __hip_bfloat16* __restrict__ mnb) {
    int b = blockIdx.x;
    int tid = threadIdx.x;
    int wave = tid >> 6, lane = tid & 63;
    __shared__ float qk_s[300];
    __shared__ float sc[50];
    __shared__ __hip_bfloat16 hs[50][304];
    if (tid < 300) qk_s[tid] = qk[(size_t)b * 320 + tid];
    __syncthreads();
    for (int k = wave; k < 50; k += 5) {
        const __hip_bfloat16* hp = h + (long)(b * 50 + k) * LDK;
        float partial = 0.f;
        #pragma unroll
        for (int i = 0; i < 5; ++i) {
            int j = lane + i * 64;
            if (j < 300) {
                __hip_bfloat16 hv = hp[j];
                hs[k][j] = hv;
                partial += __bfloat162float(hv) * qk_s[j];
            }
        }
        #pragma unroll
        for (int s = 32; s > 0; s >>= 1) partial += __shfl_xor(partial, s, 64);
        if (lane == 0) sc[k] = partial * (1.f / 16.f);
    }
    __syncthreads();
    if (tid == 0) {
        float mx = sc[0];
        for (int k = 1; k < 50; ++k) mx = fmaxf(mx, sc[k]);
        float s = 0.f;
        for (int k = 0; k < 50; ++k) { float e = __expf(sc[k] - mx); sc[k] = e; s += e; }
        float inv = 1.f / s;
        for (int k = 0; k < 50; ++k) sc[k] *= inv;
    }
    __syncthreads();
    if (tid < 300) {
        float aw = 0.f, am = 0.f;
        for (int k = 0; k < 50; ++k) {
            float v = __bfloat162float(hs[k][tid]);
            aw += sc[k] * v;
            am += v;
        }
        wpb[(size_t)b * 320 + tid] = __float2bfloat16(aw);
        mnb[(size_t)b * 320 + tid] = __float2bfloat16(am * (1.f / 50.f));
    }
}

// ---------------- combine: f = relu(att) + metal2 + relu(lig + lg_b), bf16 ----------------
__global__ void k_comb(const float* __restrict__ attb, const float* __restrict__ ligb,
                       const float* __restrict__ metal2, const float* __restrict__ lg_bias,
                       __hip_bfloat16* __restrict__ fb) {
    int idx = blockIdx.x * 256 + threadIdx.x;
    if (idx >= 1000 * 256) return;
    int c = idx & 255;
    float f = fmaxf(attb[idx], 0.f) + metal2[idx] + fmaxf(ligb[idx] + lg_bias[c], 0.f);
    fb[idx] = __float2bfloat16(f);
}

// ---------------- out: softplus(a + ph1b) . ph2w + ph2b ----------------
__global__ __launch_bounds__(512) void k_out(const float* __restrict__ a2, const float* __restrict__ ph1b,
                                             const float* __restrict__ ph2w, const float* __restrict__ ph2b,
                                             float* __restrict__ out) {
    int b = blockIdx.x, t = threadIdx.x;
    int lane = t & 63, wv = t >> 6;
    float a = a2[(size_t)b * 512 + t] + ph1b[t];
    float sp = fmaxf(a, 0.f) + log1pf(__expf(-fabsf(a)));
    float r = sp * ph2w[t];
    #pragma unroll
    for (int s = 32; s > 0; s >>= 1) r += __shfl_xor(r, s, 64);
    __shared__ float red[8];
    if (lane == 0) red[wv] = r;
    __syncthreads();
    if (t == 0) {
        float s = 0.f;
        #pragma unroll
        for (int i = 0; i < 8; ++i) s += red[i];
        out[b] = s + ph2b[0];
    }
}

extern "C" void kernel_launch(void* const* d_in, const int* in_sizes, int n_in,
                              void* d_out, int out_size, void* d_ws, size_t ws_size,
                              hipStream_t stream) {
    const int*   x_type   = (const int*)d_in[0];
    const float* x_feat   = (const float*)d_in[1];
    const int*   eindex   = (const int*)d_in[2];
    const float* eattr    = (const float*)d_in[3];
    const int*   mtype    = (const int*)d_in[4];
    const float* mfeat    = (const float*)d_in[5];
    const float* x_emb    = (const float*)d_in[6];
    const float* x_weight = (const float*)d_in[7];
    const float* ew1      = (const float*)d_in[8];
    const float* mlp_w    = (const float*)d_in[9];
    const float* mlp_b    = (const float*)d_in[10];
    const float* bn_g     = (const float*)d_in[11];
    const float* bn_b     = (const float*)d_in[12];
    const float* bn_rm    = (const float*)d_in[13];
    const float* bn_rv    = (const float*)d_in[14];
    const float* me1_w    = (const float*)d_in[15];
    const float* me1_b    = (const float*)d_in[16];
    const float* me2      = (const float*)d_in[17];
    const float* wq       = (const float*)d_in[18];
    const float* wk       = (const float*)d_in[19];
    const float* wv       = (const float*)d_in[20];
    const float* ml_w     = (const float*)d_in[21];
    const float* ml_b     = (const float*)d_in[22];
    const float* lg_w     = (const float*)d_in[23];
    const float* lg_b     = (const float*)d_in[24];
    const float* ph1_w    = (const float*)d_in[25];
    const float* ph1_b    = (const float*)d_in[26];
    const float* ph2_w    = (const float*)d_in[27];
    const float* ph2_b    = (const float*)d_in[28];

    char* ws = (char*)d_ws;
    size_t o = 0;
    auto alloc = [&](size_t bytes) -> void* {
        void* p = ws + o;
        o += (bytes + 255) & ~(size_t)255;
        return p;
    };
    __hip_bfloat16* h    = (__hip_bfloat16*)alloc((size_t)MPAD * LDK * 2);
    __hip_bfloat16* mh   = (__hip_bfloat16*)alloc((size_t)MPAD * LDK * 2);
    __hip_bfloat16* wb   = (__hip_bfloat16*)alloc((size_t)5 * 320 * 320 * 2);
    int*     cnt    = (int*)alloc((size_t)NNODES * 4);
    int*     offs   = (int*)alloc((size_t)(NNODES + 1) * 4);
    int*     cur    = (int*)alloc((size_t)NNODES * 4);
    int*     bsum   = (int*)alloc((size_t)64 * 4);
    EdgeRec* pack   = (EdgeRec*)alloc((size_t)NTOT * sizeof(EdgeRec));
    float*   prm    = (float*)alloc((size_t)NLAYERS * 1520 * 4);
    float*   metal2 = (float*)alloc((size_t)1000 * 256 * 4);
    float*   qk     = (float*)alloc((size_t)1024 * 320 * 4);
    float*   me1wT  = (float*)alloc((size_t)17 * 300 * 4);
    __hip_bfloat16* mfb  = (__hip_bfloat16*)alloc((size_t)1024 * 320 * 2);
    __hip_bfloat16* wcat = (__hip_bfloat16*)alloc((size_t)512 * 320 * 2);
    __hip_bfloat16* wkTb = (__hip_bfloat16*)alloc((size_t)320 * 256 * 2);
    __hip_bfloat16* qb   = (__hip_bfloat16*)alloc((size_t)1024 * 256 * 2);
    __hip_bfloat16* xfb  = (__hip_bfloat16*)alloc((size_t)MPAD * 32 * 2);
    __hip_bfloat16* xwTb = (__hip_bfloat16*)alloc((size_t)320 * 32 * 2);
    __hip_bfloat16* wvB  = (__hip_bfloat16*)alloc((size_t)256 * 320 * 2);
    __hip_bfloat16* lgwB = (__hip_bfloat16*)alloc((size_t)256 * 320 * 2);
    __hip_bfloat16* ph1wb= (__hip_bfloat16*)alloc((size_t)512 * 256 * 2);
    __hip_bfloat16* wpb  = (__hip_bfloat16*)alloc((size_t)1024 * 320 * 2);
    __hip_bfloat16* mnb  = (__hip_bfloat16*)alloc((size_t)1024 * 320 * 2);
    float*   attb   = (float*)alloc((size_t)1024 * 256 * 4);
    float*   ligb   = (float*)alloc((size_t)1024 * 256 * 4);
    __hip_bfloat16* fb = (__hip_bfloat16*)alloc((size_t)1024 * 256 * 2);
    float*   a2     = (float*)alloc((size_t)1024 * 512 * 4);
    (void)ws_size; (void)in_sizes; (void)n_in; (void)out_size;

    hipMemsetAsync(cnt, 0, (size_t)NNODES * 4, stream);
    hipMemsetAsync(cur, 0, (size_t)NNODES * 4, stream);
    hipMemsetAsync(mfb, 0, (size_t)1024 * 320 * 2, stream);

    k_cvt<<<(5 * 320 * 320 + 255) / 256, 256, 0, stream>>>(mlp_w, wb);
    k_cvt2<<<(512 * 320 + 320 * 256 + 255) / 256, 256, 0, stream>>>(wq, ml_w, wk, wcat, wkTb);
    k_cvt3<<<(1911788 + 255) / 256, 256, 0, stream>>>(x_feat, x_weight, wv, lg_w, ph1_w, me1_w,
                                                      xfb, xwTb, wvB, lgwB, ph1wb, me1wT);
    k_initg<<<784, 256, 0, stream>>>(xfb, xwTb, x_type, x_emb, h);
    k_count<<<(NTOT + 255) / 256, 256, 0, stream>>>(eindex, cnt);
    k_scan1<<<NSCAN, 1024, 0, stream>>>(cnt, offs, bsum);
    k_scan2<<<1, 64, 0, stream>>>(bsum);
    k_scan3<<<NSCAN, 1024, 0, stream>>>(offs, bsum);
    k_fill<<<(NTOT + 255) / 256, 256, 0, stream>>>(eindex, eattr, offs, cur, pack);
    {
        dim3 gp(300, NLAYERS);
        k_prep<<<gp, 64, 0, stream>>>(mlp_w, ew1, mlp_b, bn_g, bn_b, bn_rm, bn_rv, prm);
    }
    // metal path: mf -> {q, metal2} -> qk  (batched MFMA GEMMs)
    k_mf<<<(1000 * 300 + 255) / 256, 256, 0, stream>>>(mtype, mfeat, me1wT, me1_b, me2, mfb);
    {
        dim3 g1(8, 8);   // M=1024, N=512, K=320
        k_mm<<<g1, 256, 0, stream>>>(mfb, 320, wcat, 320, 320, 0, ml_b, qb, metal2, qk);
        dim3 g2(8, 5);   // M=1024, N=320, K=256
        k_mm<<<g2, 256, 0, stream>>>(qb, 256, wkTb, 256, 256, 1, ml_b, qb, metal2, qk);
    }

    for (int l = 0; l < NLAYERS; ++l) {
        k_gemm<<<784, 256, 0, stream>>>(h, wb + (size_t)l * 102400, mh);
        int aggr_grid = (NNODES + 4 * NPW - 1) / (4 * NPW);
        k_aggr<<<aggr_grid, 256, 0, stream>>>(mh, pack, offs, prm + (size_t)l * 1520, h,
                                              (l < NLAYERS - 1) ? 1 : 0);
    }

    k_pool<<<1000, 320, 0, stream>>>(h, qk, wpb, mnb);
    {
        dim3 ga(8, 4);   // M=1024, N=256, K=320
        k_mm2<<<ga, 256, 0, stream>>>(wpb, 320, wvB, 320, 320, attb, 256);
        k_mm2<<<ga, 256, 0, stream>>>(mnb, 320, lgwB, 320, 320, ligb, 256);
        k_comb<<<(1000 * 256 + 255) / 256, 256, 0, stream>>>(attb, ligb, metal2, lg_b, fb);
        dim3 gph(8, 8);  // M=1024, N=512, K=256
        k_mm2<<<gph, 256, 0, stream>>>(fb, 256, ph1wb, 256, 256, a2, 512);
        k_out<<<1000, 512, 0, stream>>>(a2, ph1_b, ph2_w, ph2_b, (float*)d_out);
    }
}

// Round 16
// 563.640 us; speedup vs baseline: 1.0243x; 1.0011x over previous
//
#include <hip/hip_runtime.h>
#include <hip/hip_bf16.h>
#include <math.h>

#define NNODES  50000
#define NEDGES  200000
#define NTOT    250000      // E + N self loops
#define EMB     300
#define LDK     320         // padded K stride (bf16 h / mh / weights)
#define MPAD    50048       // 391 * 128 (GEMM M padding)
#define NLAYERS 5
#define NSCAN   49          // ceil(NNODES / 1024)
#define NPW     8           // nodes per wave in k_aggr (amortize prm prologue)

struct EdgeRec { int r; float c0, c1; };

typedef __attribute__((ext_vector_type(8))) short short8;
typedef __attribute__((ext_vector_type(4))) float floatx4;
typedef __attribute__((ext_vector_type(2))) float floatx2;

__device__ inline void gll16(const void* g, void* s) {
    __builtin_amdgcn_global_load_lds((const __attribute__((address_space(1))) unsigned*)g,
                                     (__attribute__((address_space(3))) unsigned*)s, 16, 0, 0);
}

// bf16x2 (packed in u32) -> float2 via bit ops (no cvt instructions)
__device__ inline floatx2 bf2f(unsigned u) {
    floatx2 r;
    r.x = __uint_as_float(u << 16);
    r.y = __uint_as_float(u & 0xffff0000u);
    return r;
}

// ---------------- weight convert: wb[l][320][320] = bf16(mlp_w[l][300][300]) zero-padded ----------------
__global__ void k_cvt(const float* __restrict__ w, __hip_bfloat16* __restrict__ wb) {
    int idx = blockIdx.x * 256 + threadIdx.x;
    if (idx >= 5 * 320 * 320) return;
    int l = idx / 102400, r = idx % 102400, n = r / 320, k = r % 320;
    float v = (n < 300 && k < 300) ? w[l * 90000 + n * 300 + k] : 0.f;
    wb[idx] = __float2bfloat16(v);
}

// ---------------- metal-path weight packs: wcat[512][320] = [wq; ml_w], wkTb[320][256] = wk^T ----------------
__global__ void k_cvt2(const float* __restrict__ wq, const float* __restrict__ ml_w,
                       const float* __restrict__ wk,
                       __hip_bfloat16* __restrict__ wcat, __hip_bfloat16* __restrict__ wkTb) {
    int idx = blockIdx.x * 256 + threadIdx.x;
    if (idx < 512 * 320) {
        int r = idx / 320, k = idx % 320;
        float v = 0.f;
        if (k < 300) v = (r < 256) ? wq[r * 300 + k] : ml_w[(r - 256) * 300 + k];
        wcat[idx] = __float2bfloat16(v);
        return;
    }
    idx -= 512 * 320;
    if (idx < 320 * 256) {
        int c = idx / 256, j = idx % 256;
        float v = (c < 300) ? wk[j * 300 + c] : 0.f;
        wkTb[idx] = __float2bfloat16(v);
    }
}

// ---------------- init/head weight packs (xfb dropped: k_initg reads x_feat directly) ----------------
// xwTb[320][32]; vgcat[512][320] = [wv; lg_w] zero-padded; ph1wb[512][256]; me1wT fp32 transpose
__global__ void k_cvt3(const float* __restrict__ xw,
                       const float* __restrict__ wv, const float* __restrict__ lg_w,
                       const float* __restrict__ ph1_w, const float* __restrict__ me1_w,
                       __hip_bfloat16* __restrict__ xwTb, __hip_bfloat16* __restrict__ vgcat,
                       __hip_bfloat16* __restrict__ ph1wb, float* __restrict__ me1wT) {
    int idx = blockIdx.x * 256 + threadIdx.x;
    if (idx < 10240) {
        int n = idx >> 5, k = idx & 31;
        xwTb[idx] = __float2bfloat16((n < 300 && k < 16) ? xw[k * 300 + n] : 0.f);
        return;
    }
    idx -= 10240;
    if (idx < 163840) {
        int r = idx / 320, k = idx % 320;
        float v = 0.f;
        if (k < 300) v = (r < 256) ? wv[r * 300 + k] : lg_w[(r - 256) * 300 + k];
        vgcat[idx] = __float2bfloat16(v);
        return;
    }
    idx -= 163840;
    if (idx < 131072) { ph1wb[idx] = __float2bfloat16(ph1_w[idx]); return; }
    idx -= 131072;
    if (idx < 5100) { int r = idx / 17, c = idx % 17; me1wT[c * 300 + r] = me1_w[idx]; }
}

// ---------------- mf = me1b + me2[mt] + mfeat @ me1wT, bf16 [1024,320] (pads pre-zeroed) ----------------
__global__ __launch_bounds__(256) void k_mf(const int* __restrict__ mt, const float* __restrict__ mfeat,
                                            const float* __restrict__ me1wT, const float* __restrict__ me1b,
                                            const float* __restrict__ me2,
                                            __hip_bfloat16* __restrict__ mfb) {
    int idx = blockIdx.x * 256 + threadIdx.x;
    if (idx >= 1000 * 300) return;
    int g = idx / 300, c = idx % 300;
    float v = me1b[c] + me2[(size_t)mt[g] * 300 + c];
    #pragma unroll
    for (int k = 0; k < 17; ++k) v += mfeat[g * 17 + k] * me1wT[k * 300 + c];
    mfb[(size_t)g * 320 + c] = __float2bfloat16(v);
}

// ---------------- generic 128x64 MFMA GEMM for metal path (modes 0/1) ----------------
__global__ __launch_bounds__(256) void k_mm(const __hip_bfloat16* __restrict__ A, int lda,
                                            const __hip_bfloat16* __restrict__ B, int ldb,
                                            int K, int mode,
                                            const float* __restrict__ mlb,
                                            __hip_bfloat16* __restrict__ qb,
                                            float* __restrict__ metal2,
                                            float* __restrict__ qkout) {
    __shared__ __hip_bfloat16 As[128 * 32];
    __shared__ __hip_bfloat16 Bs[64 * 32];
    int tid = threadIdx.x, lane = tid & 63, w = tid >> 6;
    int row0 = blockIdx.x * 128, col0 = blockIdx.y * 64;

    floatx4 acc[2][4];
    #pragma unroll
    for (int i = 0; i < 2; ++i)
        #pragma unroll
        for (int j = 0; j < 4; ++j) acc[i][j] = (floatx4){0.f, 0.f, 0.f, 0.f};

    const __hip_bfloat16* ga0 = A + (size_t)(row0 + w * 32 + (lane >> 2)) * lda + (lane & 3) * 8;
    const __hip_bfloat16* ga1 = ga0 + (size_t)16 * lda;
    const __hip_bfloat16* gb  = B + (size_t)(col0 + w * 16 + (lane >> 2)) * ldb + (lane & 3) * 8;
    __hip_bfloat16* sa0 = &As[(w * 32) * 32];
    __hip_bfloat16* sa1 = &As[(w * 32 + 16) * 32];
    __hip_bfloat16* sb  = &Bs[(w * 16) * 32];

    int m15 = lane & 15, kof = (lane >> 4) * 8;

    for (int k0 = 0; k0 < K; k0 += 32) {
        __syncthreads();
        gll16(ga0 + k0, sa0);
        gll16(ga1 + k0, sa1);
        gll16(gb  + k0, sb);
        __syncthreads();

        short8 a[2], b[4];
        a[0] = *(const short8*)&As[(w * 32 +      m15) * 32 + kof];
        a[1] = *(const short8*)&As[(w * 32 + 16 + m15) * 32 + kof];
        #pragma unroll
        for (int nt = 0; nt < 4; ++nt)
            b[nt] = *(const short8*)&Bs[(nt * 16 + m15) * 32 + kof];

        #pragma unroll
        for (int mt = 0; mt < 2; ++mt)
            #pragma unroll
            for (int nt = 0; nt < 4; ++nt)
                acc[mt][nt] = __builtin_amdgcn_mfma_f32_16x16x32_bf16(a[mt], b[nt], acc[mt][nt], 0, 0, 0);
    }

    int rbase = row0 + w * 32 + (lane >> 4) * 4;
    #pragma unroll
    for (int mt = 0; mt < 2; ++mt)
        #pragma unroll
        for (int i = 0; i < 4; ++i) {
            int gr = rbase + mt * 16 + i;
            #pragma unroll
            for (int nt = 0; nt < 4; ++nt) {
                int gc = col0 + nt * 16 + m15;
                float v = acc[mt][nt][i];
                if (mode == 0) {
                    if (gc < 256) qb[(size_t)gr * 256 + gc] = __float2bfloat16(v);
                    else if (gr < 1000) metal2[(size_t)gr * 256 + (gc - 256)] = fmaxf(v + mlb[gc - 256], 0.f);
                } else {
                    if (gc < 300 && gr < 1000) qkout[(size_t)gr * 320 + gc] = v;
                }
            }
        }
}

// ---------------- generic 128x64 MFMA GEMM, raw fp32 store ----------------
__global__ __launch_bounds__(256) void k_mm2(const __hip_bfloat16* __restrict__ A, int lda,
                                             const __hip_bfloat16* __restrict__ B, int ldb,
                                             int K, float* __restrict__ C, int ldc) {
    __shared__ __hip_bfloat16 As[128 * 32];
    __shared__ __hip_bfloat16 Bs[64 * 32];
    int tid = threadIdx.x, lane = tid & 63, w = tid >> 6;
    int row0 = blockIdx.x * 128, col0 = blockIdx.y * 64;

    floatx4 acc[2][4];
    #pragma unroll
    for (int i = 0; i < 2; ++i)
        #pragma unroll
        for (int j = 0; j < 4; ++j) acc[i][j] = (floatx4){0.f, 0.f, 0.f, 0.f};

    const __hip_bfloat16* ga0 = A + (size_t)(row0 + w * 32 + (lane >> 2)) * lda + (lane & 3) * 8;
    const __hip_bfloat16* ga1 = ga0 + (size_t)16 * lda;
    const __hip_bfloat16* gb  = B + (size_t)(col0 + w * 16 + (lane >> 2)) * ldb + (lane & 3) * 8;
    __hip_bfloat16* sa0 = &As[(w * 32) * 32];
    __hip_bfloat16* sa1 = &As[(w * 32 + 16) * 32];
    __hip_bfloat16* sb  = &Bs[(w * 16) * 32];

    int m15 = lane & 15, kof = (lane >> 4) * 8;

    for (int k0 = 0; k0 < K; k0 += 32) {
        __syncthreads();
        gll16(ga0 + k0, sa0);
        gll16(ga1 + k0, sa1);
        gll16(gb  + k0, sb);
        __syncthreads();

        short8 a[2], b[4];
        a[0] = *(const short8*)&As[(w * 32 +      m15) * 32 + kof];
        a[1] = *(const short8*)&As[(w * 32 + 16 + m15) * 32 + kof];
        #pragma unroll
        for (int nt = 0; nt < 4; ++nt)
            b[nt] = *(const short8*)&Bs[(nt * 16 + m15) * 32 + kof];

        #pragma unroll
        for (int mt = 0; mt < 2; ++mt)
            #pragma unroll
            for (int nt = 0; nt < 4; ++nt)
                acc[mt][nt] = __builtin_amdgcn_mfma_f32_16x16x32_bf16(a[mt], b[nt], acc[mt][nt], 0, 0, 0);
    }

    int rbase = row0 + w * 32 + (lane >> 4) * 4;
    #pragma unroll
    for (int mt = 0; mt < 2; ++mt)
        #pragma unroll
        for (int i = 0; i < 4; ++i) {
            int gr = rbase + mt * 16 + i;
            #pragma unroll
            for (int nt = 0; nt < 4; ++nt)
                C[(size_t)gr * ldc + col0 + nt * 16 + m15] = acc[mt][nt][i];
        }
}

// ---------------- fused head GEMM: C[1024,512]; cols<256: wpb@wv^T, cols>=256: mnb@lg_w^T ----------------
__global__ __launch_bounds__(256) void k_mmh(const __hip_bfloat16* __restrict__ wpb,
                                             const __hip_bfloat16* __restrict__ mnb,
                                             const __hip_bfloat16* __restrict__ vgcat,
                                             float* __restrict__ C) {
    __shared__ __hip_bfloat16 As[128 * 32];
    __shared__ __hip_bfloat16 Bs[64 * 32];
    int tid = threadIdx.x, lane = tid & 63, w = tid >> 6;
    int row0 = blockIdx.x * 128, col0 = blockIdx.y * 64;
    const __hip_bfloat16* A = (blockIdx.y < 4) ? wpb : mnb;

    floatx4 acc[2][4];
    #pragma unroll
    for (int i = 0; i < 2; ++i)
        #pragma unroll
        for (int j = 0; j < 4; ++j) acc[i][j] = (floatx4){0.f, 0.f, 0.f, 0.f};

    const __hip_bfloat16* ga0 = A + (size_t)(row0 + w * 32 + (lane >> 2)) * 320 + (lane & 3) * 8;
    const __hip_bfloat16* ga1 = ga0 + (size_t)16 * 320;
    const __hip_bfloat16* gb  = vgcat + (size_t)(col0 + w * 16 + (lane >> 2)) * 320 + (lane & 3) * 8;
    __hip_bfloat16* sa0 = &As[(w * 32) * 32];
    __hip_bfloat16* sa1 = &As[(w * 32 + 16) * 32];
    __hip_bfloat16* sb  = &Bs[(w * 16) * 32];

    int m15 = lane & 15, kof = (lane >> 4) * 8;

    for (int k0 = 0; k0 < 320; k0 += 32) {
        __syncthreads();
        gll16(ga0 + k0, sa0);
        gll16(ga1 + k0, sa1);
        gll16(gb  + k0, sb);
        __syncthreads();

        short8 a[2], b[4];
        a[0] = *(const short8*)&As[(w * 32 +      m15) * 32 + kof];
        a[1] = *(const short8*)&As[(w * 32 + 16 + m15) * 32 + kof];
        #pragma unroll
        for (int nt = 0; nt < 4; ++nt)
            b[nt] = *(const short8*)&Bs[(nt * 16 + m15) * 32 + kof];

        #pragma unroll
        for (int mt = 0; mt < 2; ++mt)
            #pragma unroll
            for (int nt = 0; nt < 4; ++nt)
                acc[mt][nt] = __builtin_amdgcn_mfma_f32_16x16x32_bf16(a[mt], b[nt], acc[mt][nt], 0, 0, 0);
    }

    int rbase = row0 + w * 32 + (lane >> 4) * 4;
    #pragma unroll
    for (int mt = 0; mt < 2; ++mt)
        #pragma unroll
        for (int i = 0; i < 4; ++i) {
            int gr = rbase + mt * 16 + i;
            #pragma unroll
            for (int nt = 0; nt < 4; ++nt)
                C[(size_t)gr * 512 + col0 + nt * 16 + m15] = acc[mt][nt][i];
        }
}

// ---------------- node init as MFMA GEMM: h = bf16(xemb[xt] + x_feat @ xwTb^T), A direct from fp32 ----------------
__global__ __launch_bounds__(256) void k_initg(const float* __restrict__ xf,
                                               const __hip_bfloat16* __restrict__ B,
                                               const int* __restrict__ xt,
                                               const float* __restrict__ xemb,
                                               __hip_bfloat16* __restrict__ h) {
    int b = blockIdx.x;
    int rowblk = (b >> 4) * 8 + (b & 7);
    if (rowblk >= 391) return;
    int row0 = rowblk * 128;
    int col0 = ((b >> 3) & 1) * 160;

    __shared__ __hip_bfloat16 Bs[160 * 32];
    int tid = threadIdx.x;
    int lane = tid & 63, w = tid >> 6;
    int m15 = lane & 15, kof = (lane >> 4) * 8;

    floatx4 acc[2][10];
    #pragma unroll
    for (int i = 0; i < 2; ++i)
        #pragma unroll
        for (int j = 0; j < 10; ++j) acc[i][j] = (floatx4){0.f, 0.f, 0.f, 0.f};

    int brow0 = (w < 2) ? w * 48 : 96 + (w - 2) * 32;
    int nb = (w < 2) ? 3 : 2;
    const __hip_bfloat16* gb = B + (size_t)(col0 + brow0 + (lane >> 2)) * 32 + (lane & 3) * 8;
    __hip_bfloat16* sb = &Bs[brow0 * 32];
    for (int i = 0; i < nb; ++i)
        gll16(gb + (size_t)i * 16 * 32, sb + i * 16 * 32);

    // A fragment straight from fp32 x_feat (K real = 16, kof in {0,8} has data)
    short8 a[2];
    #pragma unroll
    for (int t = 0; t < 2; ++t) {
        int gr = row0 + w * 32 + t * 16 + m15;
        alignas(16) __hip_bfloat16 tmp[8];
        if (kof < 16 && gr < NNODES) {
            const float4* xp = (const float4*)(xf + (size_t)gr * 16 + kof);
            float4 f0 = xp[0], f1 = xp[1];
            tmp[0] = __float2bfloat16(f0.x); tmp[1] = __float2bfloat16(f0.y);
            tmp[2] = __float2bfloat16(f0.z); tmp[3] = __float2bfloat16(f0.w);
            tmp[4] = __float2bfloat16(f1.x); tmp[5] = __float2bfloat16(f1.y);
            tmp[6] = __float2bfloat16(f1.z); tmp[7] = __float2bfloat16(f1.w);
        } else {
            #pragma unroll
            for (int i = 0; i < 8; ++i) tmp[i] = __float2bfloat16(0.f);
        }
        a[t] = *(const short8*)tmp;
    }
    __syncthreads();

    short8 bb[10];
    #pragma unroll
    for (int nt = 0; nt < 10; ++nt)
        bb[nt] = *(const short8*)&Bs[(nt * 16 + m15) * 32 + kof];

    #pragma unroll
    for (int mt = 0; mt < 2; ++mt)
        #pragma unroll
        for (int nt = 0; nt < 10; ++nt)
            acc[mt][nt] = __builtin_amdgcn_mfma_f32_16x16x32_bf16(a[mt], bb[nt], acc[mt][nt], 0, 0, 0);

    int rbase = row0 + w * 32 + (lane >> 4) * 4;
    #pragma unroll
    for (int mt = 0; mt < 2; ++mt)
        #pragma unroll
        for (int i = 0; i < 4; ++i) {
            int gr = rbase + mt * 16 + i;
            if (gr < NNODES) {
                const float* er = xemb + (size_t)xt[gr] * 300;
                #pragma unroll
                for (int nt = 0; nt < 10; ++nt) {
                    int gc = col0 + nt * 16 + m15;
                    if (gc < 300)
                        h[(size_t)gr * LDK + gc] = __float2bfloat16(acc[mt][nt][i] + er[gc]);
                }
            }
        }
}

// ---------------- CSR build ----------------
__global__ void k_count(const int* __restrict__ ei, int* __restrict__ cnt) {
    int e = blockIdx.x * blockDim.x + threadIdx.x;
    if (e >= NTOT) return;
    int c = (e < NEDGES) ? ei[NEDGES + e] : (e - NEDGES);
    atomicAdd(&cnt[c], 1);
}

__global__ __launch_bounds__(1024) void k_scan1(const int* __restrict__ cnt, int* __restrict__ off,
                                                int* __restrict__ bsum) {
    int tid = threadIdx.x;
    int gid = blockIdx.x * 1024 + tid;
    int lane = tid & 63, wv = tid >> 6;
    int v = (gid < NNODES) ? cnt[gid] : 0;
    int x = v;
    #pragma unroll
    for (int s = 1; s < 64; s <<= 1) {
        int t = __shfl_up(x, s, 64);
        if (lane >= s) x += t;
    }
    __shared__ int wsum[16];
    if (lane == 63) wsum[wv] = x;
    __syncthreads();
    if (wv == 0) {
        int w = (lane < 16) ? wsum[lane] : 0;
        #pragma unroll
        for (int s = 1; s < 16; s <<= 1) {
            int t = __shfl_up(w, s, 64);
            if (lane >= s) w += t;
        }
        if (lane < 16) wsum[lane] = w;
    }
    __syncthreads();
    int base = (wv > 0) ? wsum[wv - 1] : 0;
    int incl = x + base;
    if (gid < NNODES) off[gid] = incl - v;
    if (tid == 1023) bsum[blockIdx.x] = incl;
}

__global__ __launch_bounds__(64) void k_scan2(int* __restrict__ bsum) {
    int lane = threadIdx.x;
    int v = (lane < NSCAN) ? bsum[lane] : 0;
    int x = v;
    #pragma unroll
    for (int s = 1; s < 64; s <<= 1) {
        int t = __shfl_up(x, s, 64);
        if (lane >= s) x += t;
    }
    if (lane < NSCAN) bsum[lane] = x - v;
}

__global__ __launch_bounds__(1024) void k_scan3(int* __restrict__ off, const int* __restrict__ bsum) {
    int gid = blockIdx.x * 1024 + threadIdx.x;
    if (gid < NNODES) off[gid] += bsum[blockIdx.x];
    if (gid == 0) off[NNODES] = NTOT;
}

__global__ void k_fill(const int* __restrict__ ei, const float* __restrict__ ea,
                       const int* __restrict__ off, int* __restrict__ cur,
                       EdgeRec* __restrict__ pack) {
    int e = blockIdx.x * blockDim.x + threadIdx.x;
    if (e >= NTOT) return;
    int r, c; float c0, c1;
    if (e < NEDGES) { r = ei[e]; c = ei[NEDGES + e]; c0 = ea[2 * e]; c1 = ea[2 * e + 1]; }
    else            { r = c = e - NEDGES; c0 = 0.f; c1 = 4.f; }
    int p = atomicAdd(&cur[c], 1);
    EdgeRec rec; rec.r = r; rec.c0 = c0; rec.c1 = c1;
    pack[off[c] + p] = rec;
}

// ---------------- per-layer precompute, all layers in one launch ----------------
__global__ __launch_bounds__(64) void k_prep(const float* __restrict__ mlp_w, const float* __restrict__ ew1,
                                             const float* __restrict__ mlp_b, const float* __restrict__ bn_g,
                                             const float* __restrict__ bn_b, const float* __restrict__ bn_rm,
                                             const float* __restrict__ bn_rv, float* __restrict__ prm) {
    int j = blockIdx.x, l = blockIdx.y;
    int lane = threadIdx.x;
    const float* W  = mlp_w + (size_t)l * 90000 + (size_t)j * 300;
    const float* ew = ew1 + l * 600;
    float a0 = 0.f, a1 = 0.f;
    #pragma unroll
    for (int i = 0; i < 5; ++i) {
        int k = lane + i * 64;
        if (k < 300) {
            float w = W[k];
            a0 += w * ew[k];
            a1 += w * ew[300 + k];
        }
    }
    #pragma unroll
    for (int s = 32; s > 0; s >>= 1) { a0 += __shfl_xor(a0, s, 64); a1 += __shfl_xor(a1, s, 64); }
    if (lane == 0) {
        float* p = prm + l * 1520;
        p[j] = a0;
        p[304 + j] = a1;
        p[608 + j] = mlp_b[l * 300 + j];
        float sc = bn_g[l * 300 + j] * rsqrtf(bn_rv[l * 300 + j] + 1e-5f);
        p[912 + j] = sc;
        p[1216 + j] = bn_b[l * 300 + j] - bn_rm[l * 300 + j] * sc;
    }
}

// ---------------- MFMA GEMM (layers): BK=32 LDS-staged 128x160 block, XCD-swizzled grid ----------------
__global__ __launch_bounds__(256) void k_gemm(const __hip_bfloat16* __restrict__ A,
                                              const __hip_bfloat16* __restrict__ B,
                                              __hip_bfloat16* __restrict__ C) {
    int b = blockIdx.x;
    int rowblk = (b >> 4) * 8 + (b & 7);
    if (rowblk >= 391) return;
    int row0 = rowblk * 128;
    int col0 = ((b >> 3) & 1) * 160;

    __shared__ __hip_bfloat16 As[128 * 32];
    __shared__ __hip_bfloat16 Bs[160 * 32];
    int tid = threadIdx.x;
    int lane = tid & 63, w = tid >> 6;

    floatx4 acc[2][10];
    #pragma unroll
    for (int i = 0; i < 2; ++i)
        #pragma unroll
        for (int j = 0; j < 10; ++j) acc[i][j] = (floatx4){0.f, 0.f, 0.f, 0.f};

    const __hip_bfloat16* ga0 = A + (size_t)(row0 + w * 32 + (lane >> 2)) * LDK + (lane & 3) * 8;
    const __hip_bfloat16* ga1 = ga0 + (size_t)16 * LDK;
    __hip_bfloat16* sa0 = &As[(w * 32) * 32];
    __hip_bfloat16* sa1 = &As[(w * 32 + 16) * 32];
    int brow0 = (w < 2) ? w * 48 : 96 + (w - 2) * 32;
    int nb = (w < 2) ? 3 : 2;
    const __hip_bfloat16* gb = B + (size_t)(col0 + brow0 + (lane >> 2)) * LDK + (lane & 3) * 8;
    __hip_bfloat16* sb = &Bs[brow0 * 32];

    int m15 = lane & 15, kof = (lane >> 4) * 8;

    for (int k0 = 0; k0 < LDK; k0 += 32) {
        __syncthreads();
        gll16(ga0 + k0, sa0);
        gll16(ga1 + k0, sa1);
        for (int i = 0; i < nb; ++i)
            gll16(gb + (size_t)i * 16 * LDK + k0, sb + i * 16 * 32);
        __syncthreads();

        short8 a[2], bb[10];
        a[0] = *(const short8*)&As[(w * 32 +      m15) * 32 + kof];
        a[1] = *(const short8*)&As[(w * 32 + 16 + m15) * 32 + kof];
        #pragma unroll
        for (int nt = 0; nt < 10; ++nt)
            bb[nt] = *(const short8*)&Bs[(nt * 16 + m15) * 32 + kof];

        #pragma unroll
        for (int mt = 0; mt < 2; ++mt)
            #pragma unroll
            for (int nt = 0; nt < 10; ++nt)
                acc[mt][nt] = __builtin_amdgcn_mfma_f32_16x16x32_bf16(a[mt], bb[nt], acc[mt][nt], 0, 0, 0);
    }

    int rbase = row0 + w * 32 + (lane >> 4) * 4;
    #pragma unroll
    for (int mt = 0; mt < 2; ++mt)
        #pragma unroll
        for (int i = 0; i < 4; ++i) {
            long gr = rbase + mt * 16 + i;
            #pragma unroll
            for (int nt = 0; nt < 10; ++nt)
                C[gr * LDK + col0 + nt * 16 + m15] = __float2bfloat16(acc[mt][nt][i]);
        }
}

// ---------------- aggregate: packed-fp32 math, wave handles NPW nodes ----------------
__global__ __launch_bounds__(256) void k_aggr(const __hip_bfloat16* __restrict__ mh,
                                              const EdgeRec* __restrict__ pack,
                                              const int* __restrict__ off, const float* __restrict__ prm,
                                              __hip_bfloat16* __restrict__ h, int do_relu) {
    int wave = threadIdx.x >> 6;
    int lane = threadIdx.x & 63;
    int n0 = (blockIdx.x * 4 + wave) * NPW;
    if (n0 >= NNODES) return;

    const floatx2 zero2 = {0.f, 0.f};
    floatx2 u0[3], u1[3], bv[3], sc[3], sh[3];
    #pragma unroll
    for (int i = 0; i < 3; ++i) {
        int j = 2 * lane + 128 * i;
        #pragma unroll
        for (int t = 0; t < 2; ++t) {
            bool ok = (j + t) < 300;
            u0[i][t] = ok ? prm[j + t]        : 0.f;
            u1[i][t] = ok ? prm[304 + j + t]  : 0.f;
            bv[i][t] = ok ? prm[608 + j + t]  : 0.f;
            sc[i][t] = ok ? prm[912 + j + t]  : 0.f;
            sh[i][t] = ok ? prm[1216 + j + t] : 0.f;
        }
    }

    int nend = (n0 + NPW < NNODES) ? n0 + NPW : NNODES;
    for (int n = n0; n < nend; ++n) {
        floatx2 acc[3];
        #pragma unroll
        for (int i = 0; i < 3; ++i) acc[i] = zero2;
        int p0 = off[n], p1 = off[n + 1];
        int p = p0;
        for (; p + 1 < p1; p += 2) {
            EdgeRec e0 = pack[p], e1 = pack[p + 1];
            const unsigned* b0 = (const unsigned*)(mh + (size_t)e0.r * LDK);
            const unsigned* b1 = (const unsigned*)(mh + (size_t)e1.r * LDK);
            unsigned raw0[3], raw1[3];
            #pragma unroll
            for (int i = 0; i < 3; ++i) {
                int j = 2 * lane + 128 * i;
                if (j < 300) {
                    raw0[i] = b0[lane + 64 * i];
                    raw1[i] = b1[lane + 64 * i];
                }
            }
            #pragma unroll
            for (int i = 0; i < 3; ++i) {
                int j = 2 * lane + 128 * i;
                if (j < 300) {
                    floatx2 t0 = e0.c0 * u0[i] + e0.c1 * u1[i] + bv[i];
                    floatx2 t1 = e1.c0 * u0[i] + e1.c1 * u1[i] + bv[i];
                    acc[i] += __builtin_elementwise_max(bf2f(raw0[i]) + t0, zero2);
                    acc[i] += __builtin_elementwise_max(bf2f(raw1[i]) + t1, zero2);
                }
            }
        }
        if (p < p1) {
            EdgeRec e0 = pack[p];
            const unsigned* b0 = (const unsigned*)(mh + (size_t)e0.r * LDK);
            #pragma unroll
            for (int i = 0; i < 3; ++i) {
                int j = 2 * lane + 128 * i;
                if (j < 300) {
                    floatx2 t0 = e0.c0 * u0[i] + e0.c1 * u1[i] + bv[i];
                    acc[i] += __builtin_elementwise_max(bf2f(b0[lane + 64 * i]) + t0, zero2);
                }
            }
        }
        #pragma unroll
        for (int i = 0; i < 3; ++i) {
            int j = 2 * lane + 128 * i;
            if (j < 300) {
                floatx2 v = acc[i] * sc[i] + sh[i];
                if (do_relu) v = __builtin_elementwise_max(v, zero2);
                __hip_bfloat162 o;
                o.x = __float2bfloat16(v.x);
                o.y = __float2bfloat16(v.y);
                *(__hip_bfloat162*)&h[(size_t)n * LDK + j] = o;
            }
        }
    }
}

// ---------------- attention pool (LDS-cached h tile) -> bf16 wpool/mean [1024x320] ----------------
__global__ __launch_bounds__(320) void k_pool(const __hip_bfloat16* __restrict__ h, const float* __restrict__ qk,
                                              __hip_bfloat16* __restrict__ wpb, __hip_bfloat16* __restrict__ mnb) {
    int b = blockIdx.x;
    int tid = threadIdx.x;
    int wave = tid >> 6, lane = tid & 63;
    __shared__ float qk_s[300];
    __shared__ float sc[50];
    __shared__ __hip_bfloat16 hs[50][304];
    if (tid < 300) qk_s[tid] = qk[(size_t)b * 320 + tid];
    __syncthreads();
    for (int k = wave; k < 50; k += 5) {
        const __hip_bfloat16* hp = h + (long)(b * 50 + k) * LDK;
        float partial = 0.f;
        #pragma unroll
        for (int i = 0; i < 5; ++i) {
            int j = lane + i * 64;
            if (j < 300) {
                __hip_bfloat16 hv = hp[j];
                hs[k][j] = hv;
                partial += __bfloat162float(hv) * qk_s[j];
            }
        }
        #pragma unroll
        for (int s = 32; s > 0; s >>= 1) partial += __shfl_xor(partial, s, 64);
        if (lane == 0) sc[k] = partial * (1.f / 16.f);
    }
    __syncthreads();
    if (tid == 0) {
        float mx = sc[0];
        for (int k = 1; k < 50; ++k) mx = fmaxf(mx, sc[k]);
        float s = 0.f;
        for (int k = 0; k < 50; ++k) { float e = __expf(sc[k] - mx); sc[k] = e; s += e; }
        float inv = 1.f / s;
        for (int k = 0; k < 50; ++k) sc[k] *= inv;
    }
    __syncthreads();
    if (tid < 300) {
        float aw = 0.f, am = 0.f;
        for (int k = 0; k < 50; ++k) {
            float v = __bfloat162float(hs[k][tid]);
            aw += sc[k] * v;
            am += v;
        }
        wpb[(size_t)b * 320 + tid] = __float2bfloat16(aw);
        mnb[(size_t)b * 320 + tid] = __float2bfloat16(am * (1.f / 50.f));
    }
}

// ---------------- combine: f = relu(att) + metal2 + relu(lig + lg_b), bf16 ----------------
__global__ void k_comb(const float* __restrict__ al, const float* __restrict__ metal2,
                       const float* __restrict__ lg_bias, __hip_bfloat16* __restrict__ fb) {
    int idx = blockIdx.x * 256 + threadIdx.x;
    if (idx >= 1000 * 256) return;
    int b = idx >> 8, c = idx & 255;
    float att = al[(size_t)b * 512 + c];
    float lig = al[(size_t)b * 512 + 256 + c];
    float f = fmaxf(att, 0.f) + metal2[idx] + fmaxf(lig + lg_bias[c], 0.f);
    fb[idx] = __float2bfloat16(f);
}

// ---------------- out: softplus(a + ph1b) . ph2w + ph2b ----------------
__global__ __launch_bounds__(512) void k_out(const float* __restrict__ a2, const float* __restrict__ ph1b,
                                             const float* __restrict__ ph2w, const float* __restrict__ ph2b,
                                             float* __restrict__ out) {
    int b = blockIdx.x, t = threadIdx.x;
    int lane = t & 63, wv = t >> 6;
    float a = a2[(size_t)b * 512 + t] + ph1b[t];
    float sp = fmaxf(a, 0.f) + log1pf(__expf(-fabsf(a)));
    float r = sp * ph2w[t];
    #pragma unroll
    for (int s = 32; s > 0; s >>= 1) r += __shfl_xor(r, s, 64);
    __shared__ float red[8];
    if (lane == 0) red[wv] = r;
    __syncthreads();
    if (t == 0) {
        float s = 0.f;
        #pragma unroll
        for (int i = 0; i < 8; ++i) s += red[i];
        out[b] = s + ph2b[0];
    }
}

extern "C" void kernel_launch(void* const* d_in, const int* in_sizes, int n_in,
                              void* d_out, int out_size, void* d_ws, size_t ws_size,
                              hipStream_t stream) {
    const int*   x_type   = (const int*)d_in[0];
    const float* x_feat   = (const float*)d_in[1];
    const int*   eindex   = (const int*)d_in[2];
    const float* eattr    = (const float*)d_in[3];
    const int*   mtype    = (const int*)d_in[4];
    const float* mfeat    = (const float*)d_in[5];
    const float* x_emb    = (const float*)d_in[6];
    const float* x_weight = (const float*)d_in[7];
    const float* ew1      = (const float*)d_in[8];
    const float* mlp_w    = (const float*)d_in[9];
    const float* mlp_b    = (const float*)d_in[10];
    const float* bn_g     = (const float*)d_in[11];
    const float* bn_b     = (const float*)d_in[12];
    const float* bn_rm    = (const float*)d_in[13];
    const float* bn_rv    = (const float*)d_in[14];
    const float* me1_w    = (const float*)d_in[15];
    const float* me1_b    = (const float*)d_in[16];
    const float* me2      = (const float*)d_in[17];
    const float* wq       = (const float*)d_in[18];
    const float* wk       = (const float*)d_in[19];
    const float* wv       = (const float*)d_in[20];
    const float* ml_w     = (const float*)d_in[21];
    const float* ml_b     = (const float*)d_in[22];
    const float* lg_w     = (const float*)d_in[23];
    const float* lg_b     = (const float*)d_in[24];
    const float* ph1_w    = (const float*)d_in[25];
    const float* ph1_b    = (const float*)d_in[26];
    const float* ph2_w    = (const float*)d_in[27];
    const float* ph2_b    = (const float*)d_in[28];

    char* ws = (char*)d_ws;
    size_t o = 0;
    auto alloc = [&](size_t bytes) -> void* {
        void* p = ws + o;
        o += (bytes + 255) & ~(size_t)255;
        return p;
    };
    __hip_bfloat16* h    = (__hip_bfloat16*)alloc((size_t)MPAD * LDK * 2);
    __hip_bfloat16* mh   = (__hip_bfloat16*)alloc((size_t)MPAD * LDK * 2);
    __hip_bfloat16* wb   = (__hip_bfloat16*)alloc((size_t)5 * 320 * 320 * 2);
    int*     cnt    = (int*)alloc((size_t)NNODES * 4);
    int*     offs   = (int*)alloc((size_t)(NNODES + 1) * 4);
    int*     cur    = (int*)alloc((size_t)NNODES * 4);
    int*     bsum   = (int*)alloc((size_t)64 * 4);
    EdgeRec* pack   = (EdgeRec*)alloc((size_t)NTOT * sizeof(EdgeRec));
    float*   prm    = (float*)alloc((size_t)NLAYERS * 1520 * 4);
    float*   metal2 = (float*)alloc((size_t)1000 * 256 * 4);
    float*   qk     = (float*)alloc((size_t)1024 * 320 * 4);
    float*   me1wT  = (float*)alloc((size_t)17 * 300 * 4);
    __hip_bfloat16* mfb  = (__hip_bfloat16*)alloc((size_t)1024 * 320 * 2);
    __hip_bfloat16* wcat = (__hip_bfloat16*)alloc((size_t)512 * 320 * 2);
    __hip_bfloat16* wkTb = (__hip_bfloat16*)alloc((size_t)320 * 256 * 2);
    __hip_bfloat16* qb   = (__hip_bfloat16*)alloc((size_t)1024 * 256 * 2);
    __hip_bfloat16* xwTb = (__hip_bfloat16*)alloc((size_t)320 * 32 * 2);
    __hip_bfloat16* vgcat= (__hip_bfloat16*)alloc((size_t)512 * 320 * 2);
    __hip_bfloat16* ph1wb= (__hip_bfloat16*)alloc((size_t)512 * 256 * 2);
    __hip_bfloat16* wpb  = (__hip_bfloat16*)alloc((size_t)1024 * 320 * 2);
    __hip_bfloat16* mnb  = (__hip_bfloat16*)alloc((size_t)1024 * 320 * 2);
    float*   al     = (float*)alloc((size_t)1024 * 512 * 4);
    __hip_bfloat16* fb = (__hip_bfloat16*)alloc((size_t)1024 * 256 * 2);
    float*   a2     = (float*)alloc((size_t)1024 * 512 * 4);
    (void)ws_size; (void)in_sizes; (void)n_in; (void)out_size;

    hipMemsetAsync(cnt, 0, (size_t)NNODES * 4, stream);
    hipMemsetAsync(cur, 0, (size_t)NNODES * 4, stream);
    hipMemsetAsync(mfb, 0, (size_t)1024 * 320 * 2, stream);

    k_cvt<<<(5 * 320 * 320 + 255) / 256, 256, 0, stream>>>(mlp_w, wb);
    k_cvt2<<<(512 * 320 + 320 * 256 + 255) / 256, 256, 0, stream>>>(wq, ml_w, wk, wcat, wkTb);
    k_cvt3<<<(310252 + 255) / 256, 256, 0, stream>>>(x_weight, wv, lg_w, ph1_w, me1_w,
                                                     xwTb, vgcat, ph1wb, me1wT);
    k_initg<<<784, 256, 0, stream>>>(x_feat, xwTb, x_type, x_emb, h);
    k_count<<<(NTOT + 255) / 256, 256, 0, stream>>>(eindex, cnt);
    k_scan1<<<NSCAN, 1024, 0, stream>>>(cnt, offs, bsum);
    k_scan2<<<1, 64, 0, stream>>>(bsum);
    k_scan3<<<NSCAN, 1024, 0, stream>>>(offs, bsum);
    k_fill<<<(NTOT + 255) / 256, 256, 0, stream>>>(eindex, eattr, offs, cur, pack);
    {
        dim3 gp(300, NLAYERS);
        k_prep<<<gp, 64, 0, stream>>>(mlp_w, ew1, mlp_b, bn_g, bn_b, bn_rm, bn_rv, prm);
    }
    // metal path: mf -> {q, metal2} -> qk  (batched MFMA GEMMs)
    k_mf<<<(1000 * 300 + 255) / 256, 256, 0, stream>>>(mtype, mfeat, me1wT, me1_b, me2, mfb);
    {
        dim3 g1(8, 8);   // M=1024, N=512, K=320
        k_mm<<<g1, 256, 0, stream>>>(mfb, 320, wcat, 320, 320, 0, ml_b, qb, metal2, qk);
        dim3 g2(8, 5);   // M=1024, N=320, K=256
        k_mm<<<g2, 256, 0, stream>>>(qb, 256, wkTb, 256, 256, 1, ml_b, qb, metal2, qk);
    }

    for (int l = 0; l < NLAYERS; ++l) {
        k_gemm<<<784, 256, 0, stream>>>(h, wb + (size_t)l * 102400, mh);
        int aggr_grid = (NNODES + 4 * NPW - 1) / (4 * NPW);
        k_aggr<<<aggr_grid, 256, 0, stream>>>(mh, pack, offs, prm + (size_t)l * 1520, h,
                                              (l < NLAYERS - 1) ? 1 : 0);
    }

    k_pool<<<1000, 320, 0, stream>>>(h, qk, wpb, mnb);
    {
        dim3 gh(8, 8);   // fused: att (cols<256) + lig (cols>=256)
        k_mmh<<<gh, 256, 0, stream>>>(wpb, mnb, vgcat, al);
        k_comb<<<(1000 * 256 + 255) / 256, 256, 0, stream>>>(al, metal2, lg_b, fb);
        dim3 gph(8, 8);  // M=1024, N=512, K=256
        k_mm2<<<gph, 256, 0, stream>>>(fb, 256, ph1wb, 256, 256, a2, 512);
        k_out<<<1000, 512, 0, stream>>>(a2, ph1_b, ph2_w, ph2_b, (float*)d_out);
    }
}